// Round 1
// baseline (299.224 us; speedup 1.0000x reference)
//
#include <hip/hip_runtime.h>

typedef unsigned short u16;
typedef __attribute__((ext_vector_type(8))) short short8;
typedef __attribute__((ext_vector_type(4))) float f32x4;

#define DIM   768
#define HEADS 12
#define HD    64
#define BATCH 8
#define SEQ   1024
#define MTOK  (BATCH*SEQ)   /* 8192 */
#define NQKV  (3*DIM)       /* 2304 */

__device__ __forceinline__ u16 f2bf(float f) {
  unsigned x = __float_as_uint(f);
  x += 0x7fffu + ((x >> 16) & 1u);      // RNE
  return (u16)(x >> 16);
}

__device__ __forceinline__ void gload16(const u16* g, u16* l) {
  __builtin_amdgcn_global_load_lds(
      (const __attribute__((address_space(1))) unsigned int*)g,
      (__attribute__((address_space(3))) unsigned int*)l, 16, 0, 0);
}

// ---------------- conversion kernels ----------------
__global__ void cvt_bf16_k(const float* __restrict__ in, u16* __restrict__ out, int n) {
  int i = blockIdx.x * 256 + threadIdx.x;
  if (i < n) out[i] = f2bf(in[i]);
}

// out[n*K + k] = bf16(in[k*N + n])   (transpose KxN -> NxK)
__global__ void cvt_t_k(const float* __restrict__ in, u16* __restrict__ out, int K, int N) {
  __shared__ u16 tile[32][33];
  int n0 = blockIdx.x * 32, k0 = blockIdx.y * 32;
  int tx = threadIdx.x & 31, ty = threadIdx.x >> 5;    // 256 thr: ty 0..7
  #pragma unroll
  for (int i = 0; i < 32; i += 8)
    tile[ty + i][tx] = f2bf(in[(size_t)(k0 + ty + i) * N + n0 + tx]);
  __syncthreads();
  #pragma unroll
  for (int i = 0; i < 32; i += 8)
    out[(size_t)(n0 + ty + i) * K + k0 + tx] = tile[tx][ty + i];
}

// ---------------- GEMM: C = A[MxK] * Bt[NxK]^T + bias ----------------
// MODE 0: scatter to q/k/vt bf16 buffers.  MODE 1: fp32 row-major out.
template <int MODE>
__global__ __launch_bounds__(256)
void gemm_bt(const u16* __restrict__ A, const u16* __restrict__ Bt,
             const float* __restrict__ bias,
             u16* __restrict__ q_b, u16* __restrict__ k_b, u16* __restrict__ vt_b,
             float* __restrict__ outF, int M, int N, int K) {
  __shared__ __align__(16) u16 lA[128 * 32];
  __shared__ __align__(16) u16 lB[128 * 32];
  const int w = threadIdx.x >> 6, lane = threadIdx.x & 63;
  const int l15 = lane & 15, quad = lane >> 4;
  const int m0 = blockIdx.y * 128, n0 = blockIdx.x * 128;
  const int wm = (w >> 1) * 64, wn = (w & 1) * 64;

  f32x4 acc[4][4] = {};

  const int rr = lane >> 2;          // 0..15  (row within 16-row slab)
  const int cc = (lane & 3) * 8;     // k-chunk of 8 bf16 = 16B
  const u16* ga0 = A  + (size_t)(m0 + w * 32 + rr) * K + cc;
  const u16* gb0 = Bt + (size_t)(n0 + w * 32 + rr) * K + cc;
  u16* la0 = &lA[w * 1024];
  u16* lb0 = &lB[w * 1024];

  for (int k0 = 0; k0 < K; k0 += 32) {
    gload16(ga0 + k0,          la0);
    gload16(ga0 + 16 * K + k0, la0 + 512);
    gload16(gb0 + k0,          lb0);
    gload16(gb0 + 16 * K + k0, lb0 + 512);
    __syncthreads();

    short8 af[4], bf[4];
    #pragma unroll
    for (int mt = 0; mt < 4; ++mt)
      af[mt] = *(const short8*)&lA[(wm + mt * 16 + l15) * 32 + quad * 8];
    #pragma unroll
    for (int nt = 0; nt < 4; ++nt)
      bf[nt] = *(const short8*)&lB[(wn + nt * 16 + l15) * 32 + quad * 8];
    #pragma unroll
    for (int mt = 0; mt < 4; ++mt)
      #pragma unroll
      for (int nt = 0; nt < 4; ++nt)
        acc[mt][nt] = __builtin_amdgcn_mfma_f32_16x16x32_bf16(af[mt], bf[nt], acc[mt][nt], 0, 0, 0);
    __syncthreads();
  }

  #pragma unroll
  for (int mt = 0; mt < 4; ++mt)
    #pragma unroll
    for (int nt = 0; nt < 4; ++nt) {
      const int n = n0 + wn + nt * 16 + l15;
      const float bn = bias[n];
      #pragma unroll
      for (int r = 0; r < 4; ++r) {
        const int m = m0 + wm + mt * 16 + quad * 4 + r;
        const float v = acc[mt][nt][r] + bn;
        if (MODE == 0) {
          const int part = n / DIM, hh = (n % DIM) >> 6, d = n & 63;
          const int b = m >> 10, t = m & 1023;
          const int bh = b * HEADS + hh;
          const u16 bv = f2bf(v);
          if (part == 0)      q_b[((size_t)bh * SEQ + t) * HD + d] = bv;
          else if (part == 1) k_b[((size_t)bh * SEQ + t) * HD + d] = bv;
          else                vt_b[((size_t)bh * HD + d) * SEQ + t] = bv;
        } else {
          outF[(size_t)m * N + n] = v;
        }
      }
    }
}

// ---------------- flash attention ----------------
// grid (16, 96): x = q-tile (64 rows), y = bh. block 256 = 4 waves x 16 q-rows.
__global__ __launch_bounds__(256)
void attn_k(const u16* __restrict__ qb, const u16* __restrict__ kb,
            const u16* __restrict__ vtb, u16* __restrict__ yb) {
  const int qt = blockIdx.x, bh = blockIdx.y;
  const int w = threadIdx.x >> 6, lane = threadIdx.x & 63;
  const int l15 = lane & 15, quad = lane >> 4;

  __shared__ __align__(16) u16 lK[64 * 64];
  __shared__ __align__(16) u16 lV[64 * 64];     // [d][key]
  __shared__ __align__(16) u16 lP[4][16 * 64];  // per-wave

  const u16* qbase = qb + ((size_t)bh * SEQ + qt * 64 + w * 16 + l15) * HD;
  const short8 aq0 = *(const short8*)(qbase + quad * 8);
  const short8 aq1 = *(const short8*)(qbase + 32 + quad * 8);

  f32x4 o[4] = {};
  float mi[4] = {-1e30f, -1e30f, -1e30f, -1e30f};
  float li[4] = {0.f, 0.f, 0.f, 0.f};

  const u16* kcbase = kb + (size_t)bh * SEQ * HD;
  const u16* vbase  = vtb + (size_t)bh * HD * SEQ;

  for (int kc = 0; kc < 16; ++kc) {
    // stage K chunk (contiguous copy) and V chunk ([d][key])
    const short8* gk = (const short8*)(kcbase + kc * 64 * HD);
    short8* sk = (short8*)lK;
    #pragma unroll
    for (int i = 0; i < 2; ++i) sk[threadIdx.x + i * 256] = gk[threadIdx.x + i * 256];
    #pragma unroll
    for (int i = 0; i < 2; ++i) {
      const int vv = threadIdx.x + i * 256;
      const int d = vv >> 3, c8 = (vv & 7) * 8;
      *(short8*)&lV[d * 64 + c8] = *(const short8*)(vbase + (size_t)d * SEQ + kc * 64 + c8);
    }
    __syncthreads();

    // S = Q K^T   (16 q-rows x 64 keys per wave)
    f32x4 s[4] = {};
    #pragma unroll
    for (int nt = 0; nt < 4; ++nt) {
      const short8 bk0 = *(const short8*)&lK[(nt * 16 + l15) * 64 + quad * 8];
      const short8 bk1 = *(const short8*)&lK[(nt * 16 + l15) * 64 + 32 + quad * 8];
      s[nt] = __builtin_amdgcn_mfma_f32_16x16x32_bf16(aq0, bk0, s[nt], 0, 0, 0);
      s[nt] = __builtin_amdgcn_mfma_f32_16x16x32_bf16(aq1, bk1, s[nt], 0, 0, 0);
    }

    // online softmax (rows = quad*4+r, cols spread over 16 lanes x 4 nt)
    float p[4][4], alpha[4];
    #pragma unroll
    for (int r = 0; r < 4; ++r) {
      float cmax = -1e30f;
      #pragma unroll
      for (int nt = 0; nt < 4; ++nt) { s[nt][r] *= 0.125f; cmax = fmaxf(cmax, s[nt][r]); }
      #pragma unroll
      for (int off = 1; off < 16; off <<= 1) cmax = fmaxf(cmax, __shfl_xor(cmax, off));
      const float mnew = fmaxf(mi[r], cmax);
      alpha[r] = __expf(mi[r] - mnew);
      float rs = 0.f;
      #pragma unroll
      for (int nt = 0; nt < 4; ++nt) { const float pe = __expf(s[nt][r] - mnew); p[nt][r] = pe; rs += pe; }
      #pragma unroll
      for (int off = 1; off < 16; off <<= 1) rs += __shfl_xor(rs, off);
      li[r] = li[r] * alpha[r] + rs;
      mi[r] = mnew;
    }

    // P: C/D layout -> LDS -> A-operand layout
    #pragma unroll
    for (int nt = 0; nt < 4; ++nt)
      #pragma unroll
      for (int r = 0; r < 4; ++r)
        lP[w][(quad * 4 + r) * 64 + nt * 16 + l15] = f2bf(p[nt][r]);
    __syncthreads();   // also guarantees P visibility before re-read

    #pragma unroll
    for (int nt = 0; nt < 4; ++nt)
      #pragma unroll
      for (int r = 0; r < 4; ++r) o[nt][r] *= alpha[r];

    const short8 ap0 = *(const short8*)&lP[w][l15 * 64 + quad * 8];
    const short8 ap1 = *(const short8*)&lP[w][l15 * 64 + 32 + quad * 8];
    #pragma unroll
    for (int nt = 0; nt < 4; ++nt) {
      const short8 bv0 = *(const short8*)&lV[(nt * 16 + l15) * 64 + quad * 8];
      const short8 bv1 = *(const short8*)&lV[(nt * 16 + l15) * 64 + 32 + quad * 8];
      o[nt] = __builtin_amdgcn_mfma_f32_16x16x32_bf16(ap0, bv0, o[nt], 0, 0, 0);
      o[nt] = __builtin_amdgcn_mfma_f32_16x16x32_bf16(ap1, bv1, o[nt], 0, 0, 0);
    }
    __syncthreads();   // protect lK/lV before next staging
  }

  const int b = bh / HEADS, h = bh % HEADS;
  #pragma unroll
  for (int nt = 0; nt < 4; ++nt)
    #pragma unroll
    for (int r = 0; r < 4; ++r) {
      const int trow = qt * 64 + w * 16 + quad * 4 + r;
      const int col = h * HD + nt * 16 + l15;
      yb[((size_t)b * SEQ + trow) * DIM + col] = f2bf(o[nt][r] / li[r]);
    }
}

// ---------------- launcher ----------------
extern "C" void kernel_launch(void* const* d_in, const int* in_sizes, int n_in,
                              void* d_out, int out_size, void* d_ws, size_t ws_size,
                              hipStream_t stream) {
  const float* x     = (const float*)d_in[0];
  const float* Wqkv  = (const float*)d_in[1];
  const float* bqkv  = (const float*)d_in[2];
  const float* Wproj = (const float*)d_in[3];
  const float* bproj = (const float*)d_in[4];
  float* out = (float*)d_out;

  u16* xb     = (u16*)d_ws;                       // 8192*768
  u16* wqkvt  = xb + (size_t)MTOK * DIM;          // 2304*768
  u16* wprojt = wqkvt + (size_t)NQKV * DIM;       // 768*768
  u16* q_b    = wprojt + (size_t)DIM * DIM;       // 96*1024*64
  u16* k_b    = q_b + (size_t)BATCH * HEADS * SEQ * HD;
  u16* vt_b   = k_b + (size_t)BATCH * HEADS * SEQ * HD;
  u16* y_b    = vt_b + (size_t)BATCH * HEADS * SEQ * HD;   // 8192*768

  cvt_bf16_k<<<(MTOK * DIM + 255) / 256, 256, 0, stream>>>(x, xb, MTOK * DIM);
  cvt_t_k<<<dim3(NQKV / 32, DIM / 32), 256, 0, stream>>>(Wqkv, wqkvt, DIM, NQKV);
  cvt_t_k<<<dim3(DIM / 32, DIM / 32), 256, 0, stream>>>(Wproj, wprojt, DIM, DIM);

  gemm_bt<0><<<dim3(NQKV / 128, MTOK / 128), 256, 0, stream>>>(
      xb, wqkvt, bqkv, q_b, k_b, vt_b, nullptr, MTOK, NQKV, DIM);

  attn_k<<<dim3(SEQ / 64, BATCH * HEADS), 256, 0, stream>>>(q_b, k_b, vt_b, y_b);

  gemm_bt<1><<<dim3(DIM / 128, MTOK / 128), 256, 0, stream>>>(
      y_b, wprojt, bproj, nullptr, nullptr, nullptr, out, MTOK, DIM, DIM);
}

// Round 2
// 287.564 us; speedup vs baseline: 1.0405x; 1.0405x over previous
//
#include <hip/hip_runtime.h>

typedef unsigned short u16;
typedef __attribute__((ext_vector_type(8))) short short8;
typedef __attribute__((ext_vector_type(4))) short short4v;
typedef __attribute__((ext_vector_type(4))) float f32x4;

#define DIM   768
#define HEADS 12
#define HD    64
#define BATCH 8
#define SEQ   1024
#define MTOK  (BATCH*SEQ)   /* 8192 */
#define NQKV  (3*DIM)       /* 2304 */
#define KPAD  72            /* 64 + 8: row stride 36 dwords, breaks 32-bank alias */

__device__ __forceinline__ u16 f2bf(float f) {
  unsigned x = __float_as_uint(f);
  x += 0x7fffu + ((x >> 16) & 1u);      // RNE
  return (u16)(x >> 16);
}

__device__ __forceinline__ void gload16(const u16* g, u16* l) {
  __builtin_amdgcn_global_load_lds(
      (const __attribute__((address_space(1))) unsigned int*)g,
      (__attribute__((address_space(3))) unsigned int*)l, 16, 0, 0);
}

// ---------------- conversion kernels ----------------
__global__ void cvt_bf16_k(const float* __restrict__ in, u16* __restrict__ out, int n4) {
  int i = blockIdx.x * 256 + threadIdx.x;
  if (i < n4) {
    float4 f = ((const float4*)in)[i];
    short4v o;
    o.x = (short)f2bf(f.x); o.y = (short)f2bf(f.y);
    o.z = (short)f2bf(f.z); o.w = (short)f2bf(f.w);
    ((short4v*)out)[i] = o;
  }
}

// out[n*K + k] = bf16(in[k*N + n])   (transpose KxN -> NxK)
__global__ void cvt_t_k(const float* __restrict__ in, u16* __restrict__ out, int K, int N) {
  __shared__ u16 tile[32][33];
  int n0 = blockIdx.x * 32, k0 = blockIdx.y * 32;
  int tx = threadIdx.x & 31, ty = threadIdx.x >> 5;    // 256 thr: ty 0..7
  #pragma unroll
  for (int i = 0; i < 32; i += 8)
    tile[ty + i][tx] = f2bf(in[(size_t)(k0 + ty + i) * N + n0 + tx]);
  __syncthreads();
  #pragma unroll
  for (int i = 0; i < 32; i += 8)
    out[(size_t)(n0 + ty + i) * K + k0 + tx] = tile[tx][ty + i];
}

// ---------------- GEMM: C = A[MxK] * Bt[NxK]^T + bias ----------------
// MODE 0: scatter to q/k/vt bf16 buffers.  MODE 1: fp32 row-major out.
template <int MODE>
__global__ __launch_bounds__(256)
void gemm_bt(const u16* __restrict__ A, const u16* __restrict__ Bt,
             const float* __restrict__ bias,
             u16* __restrict__ q_b, u16* __restrict__ k_b, u16* __restrict__ vt_b,
             float* __restrict__ outF, int M, int N, int K) {
  __shared__ __align__(16) u16 lA[128 * 32];
  __shared__ __align__(16) u16 lB[128 * 32];
  const int w = threadIdx.x >> 6, lane = threadIdx.x & 63;
  const int l15 = lane & 15, quad = lane >> 4;
  const int m0 = blockIdx.y * 128, n0 = blockIdx.x * 128;
  const int wm = (w >> 1) * 64, wn = (w & 1) * 64;

  f32x4 acc[4][4] = {};

  const int rr = lane >> 2;          // 0..15  (row within 16-row slab)
  const int cc = (lane & 3) * 8;     // k-chunk of 8 bf16 = 16B
  const u16* ga0 = A  + (size_t)(m0 + w * 32 + rr) * K + cc;
  const u16* gb0 = Bt + (size_t)(n0 + w * 32 + rr) * K + cc;
  u16* la0 = &lA[w * 1024];
  u16* lb0 = &lB[w * 1024];

  for (int k0 = 0; k0 < K; k0 += 32) {
    gload16(ga0 + k0,          la0);
    gload16(ga0 + 16 * K + k0, la0 + 512);
    gload16(gb0 + k0,          lb0);
    gload16(gb0 + 16 * K + k0, lb0 + 512);
    __syncthreads();

    short8 af[4], bf[4];
    #pragma unroll
    for (int mt = 0; mt < 4; ++mt)
      af[mt] = *(const short8*)&lA[(wm + mt * 16 + l15) * 32 + quad * 8];
    #pragma unroll
    for (int nt = 0; nt < 4; ++nt)
      bf[nt] = *(const short8*)&lB[(wn + nt * 16 + l15) * 32 + quad * 8];
    #pragma unroll
    for (int mt = 0; mt < 4; ++mt)
      #pragma unroll
      for (int nt = 0; nt < 4; ++nt)
        acc[mt][nt] = __builtin_amdgcn_mfma_f32_16x16x32_bf16(af[mt], bf[nt], acc[mt][nt], 0, 0, 0);
    __syncthreads();
  }

  #pragma unroll
  for (int mt = 0; mt < 4; ++mt)
    #pragma unroll
    for (int nt = 0; nt < 4; ++nt) {
      const int n = n0 + wn + nt * 16 + l15;
      const float bn = bias[n];
      #pragma unroll
      for (int r = 0; r < 4; ++r) {
        const int m = m0 + wm + mt * 16 + quad * 4 + r;
        const float v = acc[mt][nt][r] + bn;
        if (MODE == 0) {
          const int part = n / DIM, hh = (n % DIM) >> 6, d = n & 63;
          const int b = m >> 10, t = m & 1023;
          const int bh = b * HEADS + hh;
          const u16 bv = f2bf(v);
          if (part == 0)      q_b[((size_t)bh * SEQ + t) * HD + d] = bv;
          else if (part == 1) k_b[((size_t)bh * SEQ + t) * HD + d] = bv;
          else                vt_b[((size_t)bh * HD + d) * SEQ + t] = bv;
        } else {
          outF[(size_t)m * N + n] = v;
        }
      }
    }
}

// ---------------- flash attention ----------------
// grid (16, 96): x = q-tile (64 rows), y = bh. block 256 = 4 waves x 16 q-rows.
__global__ __launch_bounds__(256)
void attn_k(const u16* __restrict__ qb, const u16* __restrict__ kb,
            const u16* __restrict__ vtb, u16* __restrict__ yb) {
  const int qt = blockIdx.x, bh = blockIdx.y;
  const int w = threadIdx.x >> 6, lane = threadIdx.x & 63;
  const int l15 = lane & 15, quad = lane >> 4;

  __shared__ __align__(16) u16 lK[64 * KPAD];     // [key][d]
  __shared__ __align__(16) u16 lV[64 * KPAD];     // [d][key]
  __shared__ __align__(16) u16 lP[4][16 * KPAD];  // per-wave [qrow][key]

  const u16* qbase = qb + ((size_t)bh * SEQ + qt * 64 + w * 16 + l15) * HD;
  const short8 aq0 = *(const short8*)(qbase + quad * 8);
  const short8 aq1 = *(const short8*)(qbase + 32 + quad * 8);

  f32x4 o[4] = {};
  float mi[4] = {-1e30f, -1e30f, -1e30f, -1e30f};
  float li[4] = {0.f, 0.f, 0.f, 0.f};

  const u16* kcbase = kb + (size_t)bh * SEQ * HD;
  const u16* vbase  = vtb + (size_t)bh * HD * SEQ;

  const float SC = 0.125f * 1.44269504f;   // hd^-0.5 * log2(e): softmax in exp2 domain

  for (int kc = 0; kc < 16; ++kc) {
    // stage K chunk [key][d] and V chunk [d][key], padded rows (stride KPAD)
    const u16* kg = kcbase + kc * 64 * HD;
    #pragma unroll
    for (int i = 0; i < 2; ++i) {
      const int cid = threadIdx.x + i * 256;             // 512 chunks of 16B
      *(short8*)&lK[(cid >> 3) * KPAD + (cid & 7) * 8] = *(const short8*)(kg + cid * 8);
    }
    #pragma unroll
    for (int i = 0; i < 2; ++i) {
      const int cid = threadIdx.x + i * 256;
      const int d = cid >> 3, c8 = (cid & 7) * 8;
      *(short8*)&lV[d * KPAD + c8] = *(const short8*)(vbase + (size_t)d * SEQ + kc * 64 + c8);
    }
    __syncthreads();

    // S = Q K^T   (16 q-rows x 64 keys per wave)
    f32x4 s[4] = {};
    #pragma unroll
    for (int nt = 0; nt < 4; ++nt) {
      const short8 bk0 = *(const short8*)&lK[(nt * 16 + l15) * KPAD + quad * 8];
      const short8 bk1 = *(const short8*)&lK[(nt * 16 + l15) * KPAD + 32 + quad * 8];
      s[nt] = __builtin_amdgcn_mfma_f32_16x16x32_bf16(aq0, bk0, s[nt], 0, 0, 0);
      s[nt] = __builtin_amdgcn_mfma_f32_16x16x32_bf16(aq1, bk1, s[nt], 0, 0, 0);
    }

    // online softmax (rows = quad*4+r, cols spread over 16 lanes x 4 nt)
    float p[4][4], alpha[4];
    #pragma unroll
    for (int r = 0; r < 4; ++r) {
      float cmax = -1e30f;
      #pragma unroll
      for (int nt = 0; nt < 4; ++nt) { s[nt][r] *= SC; cmax = fmaxf(cmax, s[nt][r]); }
      #pragma unroll
      for (int off = 1; off < 16; off <<= 1) cmax = fmaxf(cmax, __shfl_xor(cmax, off));
      const float mnew = fmaxf(mi[r], cmax);
      alpha[r] = exp2f(mi[r] - mnew);
      float rs = 0.f;
      #pragma unroll
      for (int nt = 0; nt < 4; ++nt) { const float pe = exp2f(s[nt][r] - mnew); p[nt][r] = pe; rs += pe; }
      #pragma unroll
      for (int off = 1; off < 16; off <<= 1) rs += __shfl_xor(rs, off);
      li[r] = li[r] * alpha[r] + rs;
      mi[r] = mnew;
    }

    // P: C/D layout -> LDS -> A-operand layout
    #pragma unroll
    for (int nt = 0; nt < 4; ++nt)
      #pragma unroll
      for (int r = 0; r < 4; ++r)
        lP[w][(quad * 4 + r) * KPAD + nt * 16 + l15] = f2bf(p[nt][r]);
    __syncthreads();   // also guarantees P visibility before re-read

    #pragma unroll
    for (int nt = 0; nt < 4; ++nt)
      #pragma unroll
      for (int r = 0; r < 4; ++r) o[nt][r] *= alpha[r];

    const short8 ap0 = *(const short8*)&lP[w][l15 * KPAD + quad * 8];
    const short8 ap1 = *(const short8*)&lP[w][l15 * KPAD + 32 + quad * 8];
    #pragma unroll
    for (int nt = 0; nt < 4; ++nt) {
      const short8 bv0 = *(const short8*)&lV[(nt * 16 + l15) * KPAD + quad * 8];
      const short8 bv1 = *(const short8*)&lV[(nt * 16 + l15) * KPAD + 32 + quad * 8];
      o[nt] = __builtin_amdgcn_mfma_f32_16x16x32_bf16(ap0, bv0, o[nt], 0, 0, 0);
      o[nt] = __builtin_amdgcn_mfma_f32_16x16x32_bf16(ap1, bv1, o[nt], 0, 0, 0);
    }
    __syncthreads();   // protect lK/lV/lP before next staging
  }

  const int b = bh / HEADS, h = bh % HEADS;
  #pragma unroll
  for (int r = 0; r < 4; ++r) {
    const float inv = 1.0f / li[r];
    #pragma unroll
    for (int nt = 0; nt < 4; ++nt) {
      const int trow = qt * 64 + w * 16 + quad * 4 + r;
      const int col = h * HD + nt * 16 + l15;
      yb[((size_t)b * SEQ + trow) * DIM + col] = f2bf(o[nt][r] * inv);
    }
  }
}

// ---------------- launcher ----------------
extern "C" void kernel_launch(void* const* d_in, const int* in_sizes, int n_in,
                              void* d_out, int out_size, void* d_ws, size_t ws_size,
                              hipStream_t stream) {
  const float* x     = (const float*)d_in[0];
  const float* Wqkv  = (const float*)d_in[1];
  const float* bqkv  = (const float*)d_in[2];
  const float* Wproj = (const float*)d_in[3];
  const float* bproj = (const float*)d_in[4];
  float* out = (float*)d_out;

  u16* xb     = (u16*)d_ws;                       // 8192*768
  u16* wqkvt  = xb + (size_t)MTOK * DIM;          // 2304*768
  u16* wprojt = wqkvt + (size_t)NQKV * DIM;       // 768*768
  u16* q_b    = wprojt + (size_t)DIM * DIM;       // 96*1024*64
  u16* k_b    = q_b + (size_t)BATCH * HEADS * SEQ * HD;
  u16* vt_b   = k_b + (size_t)BATCH * HEADS * SEQ * HD;
  u16* y_b    = vt_b + (size_t)BATCH * HEADS * SEQ * HD;   // 8192*768

  cvt_bf16_k<<<(MTOK * DIM / 4 + 255) / 256, 256, 0, stream>>>(x, xb, MTOK * DIM / 4);
  cvt_t_k<<<dim3(NQKV / 32, DIM / 32), 256, 0, stream>>>(Wqkv, wqkvt, DIM, NQKV);
  cvt_t_k<<<dim3(DIM / 32, DIM / 32), 256, 0, stream>>>(Wproj, wprojt, DIM, DIM);

  gemm_bt<0><<<dim3(NQKV / 128, MTOK / 128), 256, 0, stream>>>(
      xb, wqkvt, bqkv, q_b, k_b, vt_b, nullptr, MTOK, NQKV, DIM);

  attn_k<<<dim3(SEQ / 64, BATCH * HEADS), 256, 0, stream>>>(q_b, k_b, vt_b, y_b);

  gemm_bt<1><<<dim3(DIM / 128, MTOK / 128), 256, 0, stream>>>(
      y_b, wprojt, bproj, nullptr, nullptr, nullptr, out, MTOK, DIM, DIM);
}

// Round 3
// 235.548 us; speedup vs baseline: 1.2703x; 1.2208x over previous
//
#include <hip/hip_runtime.h>

typedef unsigned short u16;
typedef __attribute__((ext_vector_type(8))) short short8;
typedef __attribute__((ext_vector_type(4))) short short4v;
typedef __attribute__((ext_vector_type(4))) float f32x4;

#define DIM   768
#define HEADS 12
#define HD    64
#define BATCH 8
#define SEQ   1024
#define MTOK  (BATCH*SEQ)   /* 8192 */
#define NQKV  (3*DIM)       /* 2304 */
#define KPAD  72            /* 64 + 8: row stride 36 dwords, breaks 32-bank alias */

__device__ __forceinline__ u16 f2bf(float f) {
  unsigned x = __float_as_uint(f);
  x += 0x7fffu + ((x >> 16) & 1u);      // RNE
  return (u16)(x >> 16);
}

__device__ __forceinline__ void gload16(const u16* g, u16* l) {
  __builtin_amdgcn_global_load_lds(
      (const __attribute__((address_space(1))) unsigned int*)g,
      (__attribute__((address_space(3))) unsigned int*)l, 16, 0, 0);
}

// ---------------- conversion kernels ----------------
__global__ void cvt_bf16_k(const float* __restrict__ in, u16* __restrict__ out, int n4) {
  int i = blockIdx.x * 256 + threadIdx.x;
  if (i < n4) {
    float4 f = ((const float4*)in)[i];
    short4v o;
    o.x = (short)f2bf(f.x); o.y = (short)f2bf(f.y);
    o.z = (short)f2bf(f.z); o.w = (short)f2bf(f.w);
    ((short4v*)out)[i] = o;
  }
}

// out[n*K + k] = bf16(in[k*N + n])   (transpose KxN -> NxK)
__global__ void cvt_t_k(const float* __restrict__ in, u16* __restrict__ out, int K, int N) {
  __shared__ u16 tile[32][33];
  int n0 = blockIdx.x * 32, k0 = blockIdx.y * 32;
  int tx = threadIdx.x & 31, ty = threadIdx.x >> 5;    // 256 thr: ty 0..7
  #pragma unroll
  for (int i = 0; i < 32; i += 8)
    tile[ty + i][tx] = f2bf(in[(size_t)(k0 + ty + i) * N + n0 + tx]);
  __syncthreads();
  #pragma unroll
  for (int i = 0; i < 32; i += 8)
    out[(size_t)(n0 + ty + i) * K + k0 + tx] = tile[tx][ty + i];
}

// ---------------- GEMM: C = A[MxK] * Bt[NxK]^T + bias ----------------
// MODE 0: scatter to q/k/vt bf16 buffers.  MODE 1: fp32 row-major out.
template <int MODE>
__global__ __launch_bounds__(256)
void gemm_bt(const u16* __restrict__ A, const u16* __restrict__ Bt,
             const float* __restrict__ bias,
             u16* __restrict__ q_b, u16* __restrict__ k_b, u16* __restrict__ vt_b,
             float* __restrict__ outF, int M, int N, int K) {
  __shared__ __align__(16) u16 lA[128 * 32];
  __shared__ __align__(16) u16 lB[128 * 32];
  const int w = threadIdx.x >> 6, lane = threadIdx.x & 63;
  const int l15 = lane & 15, quad = lane >> 4;
  const int m0 = blockIdx.y * 128, n0 = blockIdx.x * 128;
  const int wm = (w >> 1) * 64, wn = (w & 1) * 64;

  f32x4 acc[4][4] = {};

  const int rr = lane >> 2;          // 0..15  (row within 16-row slab)
  const int cc = (lane & 3) * 8;     // k-chunk of 8 bf16 = 16B
  const u16* ga0 = A  + (size_t)(m0 + w * 32 + rr) * K + cc;
  const u16* gb0 = Bt + (size_t)(n0 + w * 32 + rr) * K + cc;
  u16* la0 = &lA[w * 1024];
  u16* lb0 = &lB[w * 1024];

  for (int k0 = 0; k0 < K; k0 += 32) {
    gload16(ga0 + k0,          la0);
    gload16(ga0 + 16 * K + k0, la0 + 512);
    gload16(gb0 + k0,          lb0);
    gload16(gb0 + 16 * K + k0, lb0 + 512);
    __syncthreads();

    short8 af[4], bf[4];
    #pragma unroll
    for (int mt = 0; mt < 4; ++mt)
      af[mt] = *(const short8*)&lA[(wm + mt * 16 + l15) * 32 + quad * 8];
    #pragma unroll
    for (int nt = 0; nt < 4; ++nt)
      bf[nt] = *(const short8*)&lB[(wn + nt * 16 + l15) * 32 + quad * 8];
    #pragma unroll
    for (int mt = 0; mt < 4; ++mt)
      #pragma unroll
      for (int nt = 0; nt < 4; ++nt)
        acc[mt][nt] = __builtin_amdgcn_mfma_f32_16x16x32_bf16(af[mt], bf[nt], acc[mt][nt], 0, 0, 0);
    __syncthreads();
  }

  #pragma unroll
  for (int mt = 0; mt < 4; ++mt)
    #pragma unroll
    for (int nt = 0; nt < 4; ++nt) {
      const int n = n0 + wn + nt * 16 + l15;
      const float bn = bias[n];
      #pragma unroll
      for (int r = 0; r < 4; ++r) {
        const int m = m0 + wm + mt * 16 + quad * 4 + r;
        const float v = acc[mt][nt][r] + bn;
        if (MODE == 0) {
          const int part = n / DIM, hh = (n % DIM) >> 6, d = n & 63;
          const int b = m >> 10, t = m & 1023;
          const int bh = b * HEADS + hh;
          const u16 bv = f2bf(v);
          if (part == 0)      q_b[((size_t)bh * SEQ + t) * HD + d] = bv;
          else if (part == 1) k_b[((size_t)bh * SEQ + t) * HD + d] = bv;
          else                vt_b[((size_t)bh * HD + d) * SEQ + t] = bv;
        } else {
          outF[(size_t)m * N + n] = v;
        }
      }
    }
}

// ---------------- flash attention (S^T layout, max-free softmax) ----------------
// grid (16, 96): x = q-tile (64 rows), y = bh. block 256 = 4 waves x 16 q-rows.
__global__ __launch_bounds__(256)
void attn_k(const u16* __restrict__ qb, const u16* __restrict__ kb,
            const u16* __restrict__ vtb, u16* __restrict__ yb) {
  const int qt = blockIdx.x, bh = blockIdx.y;
  const int w = threadIdx.x >> 6, lane = threadIdx.x & 63;
  const int l15 = lane & 15, quad = lane >> 4;

  __shared__ __align__(16) u16 lK[64 * KPAD];     // [key][d]
  __shared__ __align__(16) u16 lV[64 * KPAD];     // [d][key]
  __shared__ __align__(16) u16 lP[4][16 * KPAD];  // per-wave [qrow][key] (wave-private!)

  // Q fragment: serves as B-operand for S^T = K * Q^T (same lane mapping as A).
  const u16* qbase = qb + ((size_t)bh * SEQ + qt * 64 + w * 16 + l15) * HD;
  const short8 aq0 = *(const short8*)(qbase + quad * 8);
  const short8 aq1 = *(const short8*)(qbase + 32 + quad * 8);

  f32x4 o[4] = {};
  float rs = 0.f;                                 // per-lane partial row-sum (qrow = l15)

  const u16* kcbase = kb + (size_t)bh * SEQ * HD;
  const u16* vbase  = vtb + (size_t)bh * HD * SEQ;

  const float SC = 0.125f * 1.44269504f;   // hd^-0.5 * log2(e): softmax in exp2 domain

  u16* lPw = &lP[w][0];

  for (int kc = 0; kc < 16; ++kc) {
    // stage K chunk [key][d] and V chunk [d][key], padded rows (stride KPAD)
    const u16* kg = kcbase + kc * 64 * HD;
    #pragma unroll
    for (int i = 0; i < 2; ++i) {
      const int cid = threadIdx.x + i * 256;             // 512 chunks of 16B
      *(short8*)&lK[(cid >> 3) * KPAD + (cid & 7) * 8] = *(const short8*)(kg + cid * 8);
    }
    #pragma unroll
    for (int i = 0; i < 2; ++i) {
      const int cid = threadIdx.x + i * 256;
      const int d = cid >> 3, c8 = (cid & 7) * 8;
      *(short8*)&lV[d * KPAD + c8] = *(const short8*)(vbase + (size_t)d * SEQ + kc * 64 + c8);
    }
    __syncthreads();

    // S^T = K Q^T: C/D has col = qrow (l15), rows = keys (nt*16 + quad*4 + r)
    f32x4 st[4] = {};
    #pragma unroll
    for (int nt = 0; nt < 4; ++nt) {
      const short8 ak0 = *(const short8*)&lK[(nt * 16 + l15) * KPAD + quad * 8];
      const short8 ak1 = *(const short8*)&lK[(nt * 16 + l15) * KPAD + 32 + quad * 8];
      st[nt] = __builtin_amdgcn_mfma_f32_16x16x32_bf16(ak0, aq0, st[nt], 0, 0, 0);
      st[nt] = __builtin_amdgcn_mfma_f32_16x16x32_bf16(ak1, aq1, st[nt], 0, 0, 0);
    }

    // max-free softmax: all 16 values in this lane belong to qrow l15.
    // exp2, per-lane sum accumulate, pack to bf16, write wave-private lP [qrow][key].
    #pragma unroll
    for (int nt = 0; nt < 4; ++nt) {
      float p0 = __builtin_amdgcn_exp2f(st[nt][0] * SC);
      float p1 = __builtin_amdgcn_exp2f(st[nt][1] * SC);
      float p2 = __builtin_amdgcn_exp2f(st[nt][2] * SC);
      float p3 = __builtin_amdgcn_exp2f(st[nt][3] * SC);
      rs += (p0 + p1) + (p2 + p3);
      short4v pk;
      pk.x = (short)f2bf(p0); pk.y = (short)f2bf(p1);
      pk.z = (short)f2bf(p2); pk.w = (short)f2bf(p3);
      *(short4v*)&lPw[l15 * KPAD + nt * 16 + quad * 4] = pk;   // ds_write_b64
    }
    // wave-private read-back (lgkmcnt ordering within wave; no barrier):
    const short8 ap0 = *(const short8*)&lPw[l15 * KPAD + quad * 8];
    const short8 ap1 = *(const short8*)&lPw[l15 * KPAD + 32 + quad * 8];

    #pragma unroll
    for (int nt = 0; nt < 4; ++nt) {
      const short8 bv0 = *(const short8*)&lV[(nt * 16 + l15) * KPAD + quad * 8];
      const short8 bv1 = *(const short8*)&lV[(nt * 16 + l15) * KPAD + 32 + quad * 8];
      o[nt] = __builtin_amdgcn_mfma_f32_16x16x32_bf16(ap0, bv0, o[nt], 0, 0, 0);
      o[nt] = __builtin_amdgcn_mfma_f32_16x16x32_bf16(ap1, bv1, o[nt], 0, 0, 0);
    }
    __syncthreads();   // lK/lV read-complete before next staging
  }

  // finalize row sums: combine the 4 quad-lanes of each qrow
  rs += __shfl_xor(rs, 16);
  rs += __shfl_xor(rs, 32);
  // o's C/D rows are qrow = quad*4+r; fetch that row's sum from lane l15'=quad*4+r
  float inv[4];
  #pragma unroll
  for (int r = 0; r < 4; ++r)
    inv[r] = 1.0f / __shfl(rs, quad * 4 + r, 16);

  const int b = bh / HEADS, h = bh % HEADS;
  #pragma unroll
  for (int r = 0; r < 4; ++r) {
    #pragma unroll
    for (int nt = 0; nt < 4; ++nt) {
      const int trow = qt * 64 + w * 16 + quad * 4 + r;
      const int col = h * HD + nt * 16 + l15;
      yb[((size_t)b * SEQ + trow) * DIM + col] = f2bf(o[nt][r] * inv[r]);
    }
  }
}

// ---------------- launcher ----------------
extern "C" void kernel_launch(void* const* d_in, const int* in_sizes, int n_in,
                              void* d_out, int out_size, void* d_ws, size_t ws_size,
                              hipStream_t stream) {
  const float* x     = (const float*)d_in[0];
  const float* Wqkv  = (const float*)d_in[1];
  const float* bqkv  = (const float*)d_in[2];
  const float* Wproj = (const float*)d_in[3];
  const float* bproj = (const float*)d_in[4];
  float* out = (float*)d_out;

  u16* xb     = (u16*)d_ws;                       // 8192*768
  u16* wqkvt  = xb + (size_t)MTOK * DIM;          // 2304*768
  u16* wprojt = wqkvt + (size_t)NQKV * DIM;       // 768*768
  u16* q_b    = wprojt + (size_t)DIM * DIM;       // 96*1024*64
  u16* k_b    = q_b + (size_t)BATCH * HEADS * SEQ * HD;
  u16* vt_b   = k_b + (size_t)BATCH * HEADS * SEQ * HD;
  u16* y_b    = vt_b + (size_t)BATCH * HEADS * SEQ * HD;   // 8192*768

  cvt_bf16_k<<<(MTOK * DIM / 4 + 255) / 256, 256, 0, stream>>>(x, xb, MTOK * DIM / 4);
  cvt_t_k<<<dim3(NQKV / 32, DIM / 32), 256, 0, stream>>>(Wqkv, wqkvt, DIM, NQKV);
  cvt_t_k<<<dim3(DIM / 32, DIM / 32), 256, 0, stream>>>(Wproj, wprojt, DIM, DIM);

  gemm_bt<0><<<dim3(NQKV / 128, MTOK / 128), 256, 0, stream>>>(
      xb, wqkvt, bqkv, q_b, k_b, vt_b, nullptr, MTOK, NQKV, DIM);

  attn_k<<<dim3(SEQ / 64, BATCH * HEADS), 256, 0, stream>>>(q_b, k_b, vt_b, y_b);

  gemm_bt<1><<<dim3(DIM / 128, MTOK / 128), 256, 0, stream>>>(
      y_b, wprojt, bproj, nullptr, nullptr, nullptr, out, MTOK, DIM, DIM);
}

// Round 4
// 229.122 us; speedup vs baseline: 1.3060x; 1.0280x over previous
//
#include <hip/hip_runtime.h>

typedef unsigned short u16;
typedef __attribute__((ext_vector_type(8))) short short8;
typedef __attribute__((ext_vector_type(4))) short short4v;
typedef __attribute__((ext_vector_type(4))) float f32x4;

#define DIM   768
#define HEADS 12
#define HD    64
#define BATCH 8
#define SEQ   1024
#define MTOK  (BATCH*SEQ)   /* 8192 */
#define NQKV  (3*DIM)       /* 2304 */
#define KPAD  72            /* attn LDS row stride: 36 dwords breaks 32-bank alias */
#define PSZ   ((size_t)BATCH*HEADS*SEQ*HD)   /* one of q/k/v: 6.29M elems */

__device__ __forceinline__ u16 f2bf(float f) {
  unsigned x = __float_as_uint(f);
  x += 0x7fffu + ((x >> 16) & 1u);      // RNE
  return (u16)(x >> 16);
}

__device__ __forceinline__ void gload16(const u16* g, u16* l) {
  __builtin_amdgcn_global_load_lds(
      (const __attribute__((address_space(1))) unsigned int*)g,
      (__attribute__((address_space(3))) unsigned int*)l, 16, 0, 0);
}

// ---------------- conversion kernels ----------------
__global__ void cvt_bf16_k(const float* __restrict__ in, u16* __restrict__ out, int n4) {
  int i = blockIdx.x * 256 + threadIdx.x;
  if (i < n4) {
    float4 f = ((const float4*)in)[i];
    short4v o;
    o.x = (short)f2bf(f.x); o.y = (short)f2bf(f.y);
    o.z = (short)f2bf(f.z); o.w = (short)f2bf(f.w);
    ((short4v*)out)[i] = o;
  }
}

// out[n*K + k] = bf16(in[k*N + n])   (transpose KxN -> NxK)
__global__ void cvt_t_k(const float* __restrict__ in, u16* __restrict__ out, int K, int N) {
  __shared__ u16 tile[32][33];
  int n0 = blockIdx.x * 32, k0 = blockIdx.y * 32;
  int tx = threadIdx.x & 31, ty = threadIdx.x >> 5;    // 256 thr: ty 0..7
  #pragma unroll
  for (int i = 0; i < 32; i += 8)
    tile[ty + i][tx] = f2bf(in[(size_t)(k0 + ty + i) * N + n0 + tx]);
  __syncthreads();
  #pragma unroll
  for (int i = 0; i < 32; i += 8)
    out[(size_t)(n0 + ty + i) * K + k0 + tx] = tile[tx][ty + i];
}

// ---------------- GEMM1: qkv = x * Wqkv^T + b, 256x128 tile ----------------
// qkv layout: [part][bh][t][d]  (uniform branch-free scatter)
__global__ __launch_bounds__(256, 2)
void gemm_qkv(const u16* __restrict__ A, const u16* __restrict__ Bt,
              const float* __restrict__ bias, u16* __restrict__ qkv) {
  __shared__ __align__(16) u16 lA[256 * 32];   // 16 KB
  __shared__ __align__(16) u16 lB[128 * 32];   //  8 KB
  const int w = threadIdx.x >> 6, lane = threadIdx.x & 63;
  const int l15 = lane & 15, quad = lane >> 4;
  const int m0 = blockIdx.y * 256, n0 = blockIdx.x * 128;
  const int wm = (w >> 1) * 128, wn = (w & 1) * 64;

  f32x4 acc[8][4] = {};

  const int ar = threadIdx.x >> 2, ak = (threadIdx.x & 3) * 8;  // 4x16B chunks per 32-elem row
  const u16* ga = A  + (size_t)(m0 + ar) * DIM + ak;
  const u16* gb = Bt + (size_t)(n0 + ar) * DIM + ak;
  u16* la = &lA[threadIdx.x * 8];
  u16* lb = &lB[threadIdx.x * 8];

  for (int k0 = 0; k0 < DIM; k0 += 32) {
    #pragma unroll
    for (int t = 0; t < 4; ++t) gload16(ga + (size_t)t * 64 * DIM + k0, la + t * 2048);
    #pragma unroll
    for (int t = 0; t < 2; ++t) gload16(gb + (size_t)t * 64 * DIM + k0, lb + t * 2048);
    __syncthreads();

    short8 af[8], bfr[4];
    #pragma unroll
    for (int mt = 0; mt < 8; ++mt)
      af[mt] = *(const short8*)&lA[(wm + mt * 16 + l15) * 32 + quad * 8];
    #pragma unroll
    for (int nt = 0; nt < 4; ++nt)
      bfr[nt] = *(const short8*)&lB[(wn + nt * 16 + l15) * 32 + quad * 8];
    #pragma unroll
    for (int mt = 0; mt < 8; ++mt)
      #pragma unroll
      for (int nt = 0; nt < 4; ++nt)
        acc[mt][nt] = __builtin_amdgcn_mfma_f32_16x16x32_bf16(af[mt], bfr[nt], acc[mt][nt], 0, 0, 0);
    __syncthreads();
  }

  const int bb = m0 >> 10;               // batch index (uniform: 256 | 1024)
  const int tb = (m0 & 1023) + wm + quad * 4;
  #pragma unroll
  for (int nt = 0; nt < 4; ++nt) {
    const int n = n0 + wn + nt * 16 + l15;
    const int part = n / DIM, idx = n - part * DIM;
    const int h = idx >> 6, d = idx & 63;
    const float bn = bias[n];
    u16* dst = qkv + part * PSZ + ((size_t)(bb * HEADS + h) * SEQ) * HD + d;
    #pragma unroll
    for (int mt = 0; mt < 8; ++mt)
      #pragma unroll
      for (int r = 0; r < 4; ++r) {
        const int t = tb + mt * 16 + r;
        dst[(size_t)t * HD] = f2bf(acc[mt][nt][r] + bn);
      }
  }
}

// ---------------- v [bh][t][d] -> vt [bh][d][t]  (bf16 transpose) ----------------
// XOR chunk swizzle (cc = dchunk ^ (trow>>3)) -> conflict-free transposed reads
__global__ void vt_k(const u16* __restrict__ v, u16* __restrict__ vt) {
  __shared__ u16 tl[64][72];
  const int bh = blockIdx.y, t0 = blockIdx.x * 64;
  #pragma unroll
  for (int i = 0; i < 2; ++i) {
    const int c = threadIdx.x + i * 256;
    const int tr = c >> 3, dc8 = c & 7;
    const int cc = dc8 ^ (tr >> 3);
    *(short8*)&tl[tr][cc * 8] = *(const short8*)(v + ((size_t)bh * SEQ + t0 + tr) * HD + dc8 * 8);
  }
  __syncthreads();
  #pragma unroll
  for (int i = 0; i < 2; ++i) {
    const int c = threadIdx.x + i * 256;
    const int dr = c >> 3, tc = (c & 7) * 8;
    short8 outv;
    #pragma unroll
    for (int j = 0; j < 8; ++j) {
      const int t = tc + j;
      const int cc = (dr >> 3) ^ (t >> 3);
      outv[j] = (short)tl[t][cc * 8 + (dr & 7)];
    }
    *(short8*)(vt + ((size_t)bh * HD + dr) * SEQ + t0 + tc) = outv;
  }
}

// ---------------- GEMM2: out = y * Wproj^T + b (fp32 out, 128x128) ----------------
__global__ __launch_bounds__(256)
void gemm_proj(const u16* __restrict__ A, const u16* __restrict__ Bt,
               const float* __restrict__ bias, float* __restrict__ outF) {
  __shared__ __align__(16) u16 lA[128 * 32];
  __shared__ __align__(16) u16 lB[128 * 32];
  const int w = threadIdx.x >> 6, lane = threadIdx.x & 63;
  const int l15 = lane & 15, quad = lane >> 4;
  const int m0 = blockIdx.y * 128, n0 = blockIdx.x * 128;
  const int wm = (w >> 1) * 64, wn = (w & 1) * 64;

  f32x4 acc[4][4] = {};

  const int rr = lane >> 2;
  const int cc = (lane & 3) * 8;
  const u16* ga0 = A  + (size_t)(m0 + w * 32 + rr) * DIM + cc;
  const u16* gb0 = Bt + (size_t)(n0 + w * 32 + rr) * DIM + cc;
  u16* la0 = &lA[w * 1024];
  u16* lb0 = &lB[w * 1024];

  for (int k0 = 0; k0 < DIM; k0 += 32) {
    gload16(ga0 + k0,            la0);
    gload16(ga0 + 16 * DIM + k0, la0 + 512);
    gload16(gb0 + k0,            lb0);
    gload16(gb0 + 16 * DIM + k0, lb0 + 512);
    __syncthreads();

    short8 af[4], bfr[4];
    #pragma unroll
    for (int mt = 0; mt < 4; ++mt)
      af[mt] = *(const short8*)&lA[(wm + mt * 16 + l15) * 32 + quad * 8];
    #pragma unroll
    for (int nt = 0; nt < 4; ++nt)
      bfr[nt] = *(const short8*)&lB[(wn + nt * 16 + l15) * 32 + quad * 8];
    #pragma unroll
    for (int mt = 0; mt < 4; ++mt)
      #pragma unroll
      for (int nt = 0; nt < 4; ++nt)
        acc[mt][nt] = __builtin_amdgcn_mfma_f32_16x16x32_bf16(af[mt], bfr[nt], acc[mt][nt], 0, 0, 0);
    __syncthreads();
  }

  #pragma unroll
  for (int nt = 0; nt < 4; ++nt) {
    const int n = n0 + wn + nt * 16 + l15;
    const float bn = bias[n];
    #pragma unroll
    for (int mt = 0; mt < 4; ++mt)
      #pragma unroll
      for (int r = 0; r < 4; ++r) {
        const int m = m0 + wm + mt * 16 + quad * 4 + r;
        outF[(size_t)m * DIM + n] = acc[mt][nt][r] + bn;
      }
  }
}

// ---------------- flash attention (S^T layout, max-free softmax) ----------------
__global__ __launch_bounds__(256)
void attn_k(const u16* __restrict__ qb, const u16* __restrict__ kb,
            const u16* __restrict__ vtb, u16* __restrict__ yb) {
  const int qt = blockIdx.x, bh = blockIdx.y;
  const int w = threadIdx.x >> 6, lane = threadIdx.x & 63;
  const int l15 = lane & 15, quad = lane >> 4;

  __shared__ __align__(16) u16 lK[64 * KPAD];     // [key][d]
  __shared__ __align__(16) u16 lV[64 * KPAD];     // [d][key]
  __shared__ __align__(16) u16 lP[4][16 * KPAD];  // per-wave [qrow][key] (wave-private)

  const u16* qbase = qb + ((size_t)bh * SEQ + qt * 64 + w * 16 + l15) * HD;
  const short8 aq0 = *(const short8*)(qbase + quad * 8);
  const short8 aq1 = *(const short8*)(qbase + 32 + quad * 8);

  f32x4 o[4] = {};
  float rs = 0.f;

  const u16* kcbase = kb + (size_t)bh * SEQ * HD;
  const u16* vbase  = vtb + (size_t)bh * HD * SEQ;

  const float SC = 0.125f * 1.44269504f;

  u16* lPw = &lP[w][0];

  for (int kc = 0; kc < 16; ++kc) {
    const u16* kg = kcbase + kc * 64 * HD;
    #pragma unroll
    for (int i = 0; i < 2; ++i) {
      const int cid = threadIdx.x + i * 256;
      *(short8*)&lK[(cid >> 3) * KPAD + (cid & 7) * 8] = *(const short8*)(kg + cid * 8);
    }
    #pragma unroll
    for (int i = 0; i < 2; ++i) {
      const int cid = threadIdx.x + i * 256;
      const int d = cid >> 3, c8 = (cid & 7) * 8;
      *(short8*)&lV[d * KPAD + c8] = *(const short8*)(vbase + (size_t)d * SEQ + kc * 64 + c8);
    }
    __syncthreads();

    f32x4 st[4] = {};
    #pragma unroll
    for (int nt = 0; nt < 4; ++nt) {
      const short8 ak0 = *(const short8*)&lK[(nt * 16 + l15) * KPAD + quad * 8];
      const short8 ak1 = *(const short8*)&lK[(nt * 16 + l15) * KPAD + 32 + quad * 8];
      st[nt] = __builtin_amdgcn_mfma_f32_16x16x32_bf16(ak0, aq0, st[nt], 0, 0, 0);
      st[nt] = __builtin_amdgcn_mfma_f32_16x16x32_bf16(ak1, aq1, st[nt], 0, 0, 0);
    }

    #pragma unroll
    for (int nt = 0; nt < 4; ++nt) {
      float p0 = __builtin_amdgcn_exp2f(st[nt][0] * SC);
      float p1 = __builtin_amdgcn_exp2f(st[nt][1] * SC);
      float p2 = __builtin_amdgcn_exp2f(st[nt][2] * SC);
      float p3 = __builtin_amdgcn_exp2f(st[nt][3] * SC);
      rs += (p0 + p1) + (p2 + p3);
      short4v pk;
      pk.x = (short)f2bf(p0); pk.y = (short)f2bf(p1);
      pk.z = (short)f2bf(p2); pk.w = (short)f2bf(p3);
      *(short4v*)&lPw[l15 * KPAD + nt * 16 + quad * 4] = pk;
    }
    const short8 ap0 = *(const short8*)&lPw[l15 * KPAD + quad * 8];
    const short8 ap1 = *(const short8*)&lPw[l15 * KPAD + 32 + quad * 8];

    #pragma unroll
    for (int nt = 0; nt < 4; ++nt) {
      const short8 bv0 = *(const short8*)&lV[(nt * 16 + l15) * KPAD + quad * 8];
      const short8 bv1 = *(const short8*)&lV[(nt * 16 + l15) * KPAD + 32 + quad * 8];
      o[nt] = __builtin_amdgcn_mfma_f32_16x16x32_bf16(ap0, bv0, o[nt], 0, 0, 0);
      o[nt] = __builtin_amdgcn_mfma_f32_16x16x32_bf16(ap1, bv1, o[nt], 0, 0, 0);
    }
    __syncthreads();
  }

  rs += __shfl_xor(rs, 16);
  rs += __shfl_xor(rs, 32);
  float inv[4];
  #pragma unroll
  for (int r = 0; r < 4; ++r)
    inv[r] = 1.0f / __shfl(rs, quad * 4 + r, 16);

  const int b = bh / HEADS, h = bh % HEADS;
  #pragma unroll
  for (int r = 0; r < 4; ++r) {
    #pragma unroll
    for (int nt = 0; nt < 4; ++nt) {
      const int trow = qt * 64 + w * 16 + quad * 4 + r;
      const int col = h * HD + nt * 16 + l15;
      yb[((size_t)b * SEQ + trow) * DIM + col] = f2bf(o[nt][r] * inv[r]);
    }
  }
}

// ---------------- launcher ----------------
extern "C" void kernel_launch(void* const* d_in, const int* in_sizes, int n_in,
                              void* d_out, int out_size, void* d_ws, size_t ws_size,
                              hipStream_t stream) {
  const float* x     = (const float*)d_in[0];
  const float* Wqkv  = (const float*)d_in[1];
  const float* bqkv  = (const float*)d_in[2];
  const float* Wproj = (const float*)d_in[3];
  const float* bproj = (const float*)d_in[4];
  float* out = (float*)d_out;

  u16* xb     = (u16*)d_ws;                       // 8192*768  (later reused as vt)
  u16* wqkvt  = xb + (size_t)MTOK * DIM;          // 2304*768
  u16* wprojt = wqkvt + (size_t)NQKV * DIM;       // 768*768
  u16* qkv_b  = wprojt + (size_t)DIM * DIM;       // 3 * 96*1024*64  [part][bh][t][d]
  u16* y_b    = qkv_b + 3 * PSZ;                  // 8192*768
  u16* vt_b   = xb;                               // reuse: x dead after gemm_qkv

  cvt_bf16_k<<<(MTOK * DIM / 4 + 255) / 256, 256, 0, stream>>>(x, xb, MTOK * DIM / 4);
  cvt_t_k<<<dim3(NQKV / 32, DIM / 32), 256, 0, stream>>>(Wqkv, wqkvt, DIM, NQKV);
  cvt_t_k<<<dim3(DIM / 32, DIM / 32), 256, 0, stream>>>(Wproj, wprojt, DIM, DIM);

  gemm_qkv<<<dim3(NQKV / 128, MTOK / 256), 256, 0, stream>>>(xb, wqkvt, bqkv, qkv_b);

  vt_k<<<dim3(SEQ / 64, BATCH * HEADS), 256, 0, stream>>>(qkv_b + 2 * PSZ, vt_b);

  attn_k<<<dim3(SEQ / 64, BATCH * HEADS), 256, 0, stream>>>(
      qkv_b, qkv_b + PSZ, vt_b, y_b);

  gemm_proj<<<dim3(DIM / 128, MTOK / 128), 256, 0, stream>>>(y_b, wprojt, bproj, out);
}

// Round 5
// 227.237 us; speedup vs baseline: 1.3168x; 1.0083x over previous
//
#include <hip/hip_runtime.h>

typedef unsigned short u16;
typedef __attribute__((ext_vector_type(8))) short short8;
typedef __attribute__((ext_vector_type(4))) short short4v;
typedef __attribute__((ext_vector_type(4))) float f32x4;

#define DIM   768
#define HEADS 12
#define HD    64
#define BATCH 8
#define SEQ   1024
#define MTOK  (BATCH*SEQ)   /* 8192 */
#define NQKV  (3*DIM)       /* 2304 */
#define KPAD  72            /* attn LDS row stride: 36 dwords breaks 32-bank alias */
#define EPAD  66            /* epilogue stage stride: 33 dwords, <=2-way banks */
#define PSZ   ((size_t)BATCH*HEADS*SEQ*HD)   /* one of q/k/v: 6.29M elems */

__device__ __forceinline__ u16 f2bf(float f) {
  unsigned x = __float_as_uint(f);
  x += 0x7fffu + ((x >> 16) & 1u);      // RNE
  return (u16)(x >> 16);
}

__device__ __forceinline__ void gload16(const u16* g, u16* l) {
  __builtin_amdgcn_global_load_lds(
      (const __attribute__((address_space(1))) unsigned int*)g,
      (__attribute__((address_space(3))) unsigned int*)l, 16, 0, 0);
}

// ---------------- conversion kernels ----------------
__global__ void cvt_bf16_k(const float* __restrict__ in, u16* __restrict__ out, int n4) {
  int i = blockIdx.x * 256 + threadIdx.x;
  if (i < n4) {
    float4 f = ((const float4*)in)[i];
    short4v o;
    o.x = (short)f2bf(f.x); o.y = (short)f2bf(f.y);
    o.z = (short)f2bf(f.z); o.w = (short)f2bf(f.w);
    ((short4v*)out)[i] = o;
  }
}

// out[n*K + k] = bf16(in[k*N + n])   (transpose KxN -> NxK)
__global__ void cvt_t_k(const float* __restrict__ in, u16* __restrict__ out, int K, int N) {
  __shared__ u16 tile[32][33];
  int n0 = blockIdx.x * 32, k0 = blockIdx.y * 32;
  int tx = threadIdx.x & 31, ty = threadIdx.x >> 5;    // 256 thr: ty 0..7
  #pragma unroll
  for (int i = 0; i < 32; i += 8)
    tile[ty + i][tx] = f2bf(in[(size_t)(k0 + ty + i) * N + n0 + tx]);
  __syncthreads();
  #pragma unroll
  for (int i = 0; i < 32; i += 8)
    out[(size_t)(n0 + ty + i) * K + k0 + tx] = tile[tx][ty + i];
}

// ---------------- GEMM1: qkv = x * Wqkv^T + b, 256x128 tile ----------------
// qkv layout: [part][bh][t][d]; epilogue via per-wave LDS transpose -> full-line stores
__global__ __launch_bounds__(256, 2)
void gemm_qkv(const u16* __restrict__ A, const u16* __restrict__ Bt,
              const float* __restrict__ bias, u16* __restrict__ qkv) {
  __shared__ __align__(16) u16 smem[256 * 32 + 128 * 32];  // lA(16K) + lB(8K), reused by epilogue
  u16* lA = smem;
  u16* lB = smem + 256 * 32;
  const int w = threadIdx.x >> 6, lane = threadIdx.x & 63;
  const int l15 = lane & 15, quad = lane >> 4;
  const int m0 = blockIdx.y * 256, n0 = blockIdx.x * 128;
  const int wm = (w >> 1) * 128, wn = (w & 1) * 64;

  f32x4 acc[8][4] = {};

  const int ar = threadIdx.x >> 2, ak = (threadIdx.x & 3) * 8;  // 4x16B chunks per 32-elem row
  const u16* ga = A  + (size_t)(m0 + ar) * DIM + ak;
  const u16* gb = Bt + (size_t)(n0 + ar) * DIM + ak;
  u16* la = &lA[threadIdx.x * 8];
  u16* lb = &lB[threadIdx.x * 8];

  for (int k0 = 0; k0 < DIM; k0 += 32) {
    #pragma unroll
    for (int t = 0; t < 4; ++t) gload16(ga + (size_t)t * 64 * DIM + k0, la + t * 2048);
    #pragma unroll
    for (int t = 0; t < 2; ++t) gload16(gb + (size_t)t * 64 * DIM + k0, lb + t * 2048);
    __syncthreads();

    short8 af[8], bfr[4];
    #pragma unroll
    for (int mt = 0; mt < 8; ++mt)
      af[mt] = *(const short8*)&lA[(wm + mt * 16 + l15) * 32 + quad * 8];
    #pragma unroll
    for (int nt = 0; nt < 4; ++nt)
      bfr[nt] = *(const short8*)&lB[(wn + nt * 16 + l15) * 32 + quad * 8];
    #pragma unroll
    for (int mt = 0; mt < 8; ++mt)
      #pragma unroll
      for (int nt = 0; nt < 4; ++nt)
        acc[mt][nt] = __builtin_amdgcn_mfma_f32_16x16x32_bf16(af[mt], bfr[nt], acc[mt][nt], 0, 0, 0);
    __syncthreads();
  }
  // after the loop-end barrier, all waves are done with lA/lB -> safe to reuse

  // wave-uniform destination: this wave's 64-wide n-half = one (part, head)
  const int bb = m0 >> 10;
  const int tb0 = (m0 & 1023) + wm;            // wave's first t
  const int nh = n0 + wn;                      // multiple of 64
  const int part = nh / DIM, idx = nh - part * DIM;
  const int h = idx >> 6;
  u16* dstbase = qkv + part * PSZ + ((size_t)(bb * HEADS + h) * SEQ + tb0) * HD;

  float bnl[4];
  #pragma unroll
  for (int nt = 0; nt < 4; ++nt) bnl[nt] = bias[nh + nt * 16 + l15];

  const int erow = lane >> 3, ec8 = (lane & 7) * 8;
  #pragma unroll
  for (int mt = 0; mt < 8; ++mt) {
    u16* ep = smem + w * (16 * EPAD) + (mt & 1) * (4 * 16 * EPAD);  // wave-private, dbuf by parity
    #pragma unroll
    for (int nt = 0; nt < 4; ++nt)
      #pragma unroll
      for (int r = 0; r < 4; ++r)
        ep[(quad * 4 + r) * EPAD + nt * 16 + l15] = f2bf(acc[mt][nt][r] + bnl[nt]);
    #pragma unroll
    for (int j = 0; j < 2; ++j) {
      const int trow = j * 8 + erow;
      short8 vrow = *(const short8*)&ep[trow * EPAD + ec8];
      *(short8*)(dstbase + (size_t)(mt * 16 + trow) * HD + ec8) = vrow;  // 1KB contiguous/instr
    }
  }
}

// ---------------- v [bh][t][d] -> vt [bh][d][t]  (bf16 transpose) ----------------
__global__ void vt_k(const u16* __restrict__ v, u16* __restrict__ vt) {
  __shared__ u16 tl[64][72];
  const int bh = blockIdx.y, t0 = blockIdx.x * 64;
  #pragma unroll
  for (int i = 0; i < 2; ++i) {
    const int c = threadIdx.x + i * 256;
    const int tr = c >> 3, dc8 = c & 7;
    const int cc = dc8 ^ (tr >> 3);
    *(short8*)&tl[tr][cc * 8] = *(const short8*)(v + ((size_t)bh * SEQ + t0 + tr) * HD + dc8 * 8);
  }
  __syncthreads();
  #pragma unroll
  for (int i = 0; i < 2; ++i) {
    const int c = threadIdx.x + i * 256;
    const int dr = c >> 3, tc = (c & 7) * 8;
    short8 outv;
    #pragma unroll
    for (int j = 0; j < 8; ++j) {
      const int t = tc + j;
      const int cc = (dr >> 3) ^ (t >> 3);
      outv[j] = (short)tl[t][cc * 8 + (dr & 7)];
    }
    *(short8*)(vt + ((size_t)bh * HD + dr) * SEQ + t0 + tc) = outv;
  }
}

// ---------------- GEMM2: out = y * Wproj^T + b (fp32 out, 128x128) ----------------
__global__ __launch_bounds__(256)
void gemm_proj(const u16* __restrict__ A, const u16* __restrict__ Bt,
               const float* __restrict__ bias, float* __restrict__ outF) {
  __shared__ __align__(16) u16 lA[128 * 32];
  __shared__ __align__(16) u16 lB[128 * 32];
  const int w = threadIdx.x >> 6, lane = threadIdx.x & 63;
  const int l15 = lane & 15, quad = lane >> 4;
  const int m0 = blockIdx.y * 128, n0 = blockIdx.x * 128;
  const int wm = (w >> 1) * 64, wn = (w & 1) * 64;

  f32x4 acc[4][4] = {};

  const int rr = lane >> 2;
  const int cc = (lane & 3) * 8;
  const u16* ga0 = A  + (size_t)(m0 + w * 32 + rr) * DIM + cc;
  const u16* gb0 = Bt + (size_t)(n0 + w * 32 + rr) * DIM + cc;
  u16* la0 = &lA[w * 1024];
  u16* lb0 = &lB[w * 1024];

  for (int k0 = 0; k0 < DIM; k0 += 32) {
    gload16(ga0 + k0,            la0);
    gload16(ga0 + 16 * DIM + k0, la0 + 512);
    gload16(gb0 + k0,            lb0);
    gload16(gb0 + 16 * DIM + k0, lb0 + 512);
    __syncthreads();

    short8 af[4], bfr[4];
    #pragma unroll
    for (int mt = 0; mt < 4; ++mt)
      af[mt] = *(const short8*)&lA[(wm + mt * 16 + l15) * 32 + quad * 8];
    #pragma unroll
    for (int nt = 0; nt < 4; ++nt)
      bfr[nt] = *(const short8*)&lB[(wn + nt * 16 + l15) * 32 + quad * 8];
    #pragma unroll
    for (int mt = 0; mt < 4; ++mt)
      #pragma unroll
      for (int nt = 0; nt < 4; ++nt)
        acc[mt][nt] = __builtin_amdgcn_mfma_f32_16x16x32_bf16(af[mt], bfr[nt], acc[mt][nt], 0, 0, 0);
    __syncthreads();
  }

  #pragma unroll
  for (int nt = 0; nt < 4; ++nt) {
    const int n = n0 + wn + nt * 16 + l15;
    const float bn = bias[n];
    #pragma unroll
    for (int mt = 0; mt < 4; ++mt)
      #pragma unroll
      for (int r = 0; r < 4; ++r) {
        const int m = m0 + wm + mt * 16 + quad * 4 + r;
        outF[(size_t)m * DIM + n] = acc[mt][nt][r] + bn;   // fp32: 64B full-line segments
      }
  }
}

// ---------------- flash attention (S^T layout, max-free softmax) ----------------
__global__ __launch_bounds__(256)
void attn_k(const u16* __restrict__ qb, const u16* __restrict__ kb,
            const u16* __restrict__ vtb, u16* __restrict__ yb) {
  const int qt = blockIdx.x, bh = blockIdx.y;
  const int w = threadIdx.x >> 6, lane = threadIdx.x & 63;
  const int l15 = lane & 15, quad = lane >> 4;

  __shared__ __align__(16) u16 lK[64 * KPAD];     // [key][d]
  __shared__ __align__(16) u16 lV[64 * KPAD];     // [d][key]
  __shared__ __align__(16) u16 lP[4][16 * KPAD];  // per-wave [qrow][key] (wave-private)

  const u16* qbase = qb + ((size_t)bh * SEQ + qt * 64 + w * 16 + l15) * HD;
  const short8 aq0 = *(const short8*)(qbase + quad * 8);
  const short8 aq1 = *(const short8*)(qbase + 32 + quad * 8);

  f32x4 o[4] = {};
  float rs = 0.f;

  const u16* kcbase = kb + (size_t)bh * SEQ * HD;
  const u16* vbase  = vtb + (size_t)bh * HD * SEQ;

  const float SC = 0.125f * 1.44269504f;

  u16* lPw = &lP[w][0];

  for (int kc = 0; kc < 16; ++kc) {
    const u16* kg = kcbase + kc * 64 * HD;
    #pragma unroll
    for (int i = 0; i < 2; ++i) {
      const int cid = threadIdx.x + i * 256;
      *(short8*)&lK[(cid >> 3) * KPAD + (cid & 7) * 8] = *(const short8*)(kg + cid * 8);
    }
    #pragma unroll
    for (int i = 0; i < 2; ++i) {
      const int cid = threadIdx.x + i * 256;
      const int d = cid >> 3, c8 = (cid & 7) * 8;
      *(short8*)&lV[d * KPAD + c8] = *(const short8*)(vbase + (size_t)d * SEQ + kc * 64 + c8);
    }
    __syncthreads();

    f32x4 st[4] = {};
    #pragma unroll
    for (int nt = 0; nt < 4; ++nt) {
      const short8 ak0 = *(const short8*)&lK[(nt * 16 + l15) * KPAD + quad * 8];
      const short8 ak1 = *(const short8*)&lK[(nt * 16 + l15) * KPAD + 32 + quad * 8];
      st[nt] = __builtin_amdgcn_mfma_f32_16x16x32_bf16(ak0, aq0, st[nt], 0, 0, 0);
      st[nt] = __builtin_amdgcn_mfma_f32_16x16x32_bf16(ak1, aq1, st[nt], 0, 0, 0);
    }

    #pragma unroll
    for (int nt = 0; nt < 4; ++nt) {
      float p0 = __builtin_amdgcn_exp2f(st[nt][0] * SC);
      float p1 = __builtin_amdgcn_exp2f(st[nt][1] * SC);
      float p2 = __builtin_amdgcn_exp2f(st[nt][2] * SC);
      float p3 = __builtin_amdgcn_exp2f(st[nt][3] * SC);
      rs += (p0 + p1) + (p2 + p3);
      short4v pk;
      pk.x = (short)f2bf(p0); pk.y = (short)f2bf(p1);
      pk.z = (short)f2bf(p2); pk.w = (short)f2bf(p3);
      *(short4v*)&lPw[l15 * KPAD + nt * 16 + quad * 4] = pk;
    }
    const short8 ap0 = *(const short8*)&lPw[l15 * KPAD + quad * 8];
    const short8 ap1 = *(const short8*)&lPw[l15 * KPAD + 32 + quad * 8];

    #pragma unroll
    for (int nt = 0; nt < 4; ++nt) {
      const short8 bv0 = *(const short8*)&lV[(nt * 16 + l15) * KPAD + quad * 8];
      const short8 bv1 = *(const short8*)&lV[(nt * 16 + l15) * KPAD + 32 + quad * 8];
      o[nt] = __builtin_amdgcn_mfma_f32_16x16x32_bf16(ap0, bv0, o[nt], 0, 0, 0);
      o[nt] = __builtin_amdgcn_mfma_f32_16x16x32_bf16(ap1, bv1, o[nt], 0, 0, 0);
    }
    __syncthreads();
  }

  rs += __shfl_xor(rs, 16);
  rs += __shfl_xor(rs, 32);
  float inv[4];
  #pragma unroll
  for (int r = 0; r < 4; ++r)
    inv[r] = 1.0f / __shfl(rs, quad * 4 + r, 16);

  // epilogue: stage 16x64 o-chunk in (dead) lPw, store full 128B rows
  #pragma unroll
  for (int nt = 0; nt < 4; ++nt)
    #pragma unroll
    for (int r = 0; r < 4; ++r)
      lPw[(quad * 4 + r) * EPAD + nt * 16 + l15] = f2bf(o[nt][r] * inv[r]);

  const int b = bh / HEADS, h = bh % HEADS;
  u16* dst = yb + ((size_t)b * SEQ + qt * 64 + w * 16) * DIM + h * HD;
  const int erow = lane >> 3, ec8 = (lane & 7) * 8;
  #pragma unroll
  for (int j = 0; j < 2; ++j) {
    const int trow = j * 8 + erow;
    short8 vrow = *(const short8*)&lPw[trow * EPAD + ec8];
    *(short8*)(dst + (size_t)trow * DIM + ec8) = vrow;   // 128B per row, 2 full lines
  }
}

// ---------------- launcher ----------------
extern "C" void kernel_launch(void* const* d_in, const int* in_sizes, int n_in,
                              void* d_out, int out_size, void* d_ws, size_t ws_size,
                              hipStream_t stream) {
  const float* x     = (const float*)d_in[0];
  const float* Wqkv  = (const float*)d_in[1];
  const float* bqkv  = (const float*)d_in[2];
  const float* Wproj = (const float*)d_in[3];
  const float* bproj = (const float*)d_in[4];
  float* out = (float*)d_out;

  u16* xb     = (u16*)d_ws;                       // 8192*768  (later reused as vt)
  u16* wqkvt  = xb + (size_t)MTOK * DIM;          // 2304*768
  u16* wprojt = wqkvt + (size_t)NQKV * DIM;       // 768*768
  u16* qkv_b  = wprojt + (size_t)DIM * DIM;       // 3 * 96*1024*64  [part][bh][t][d]
  u16* y_b    = qkv_b + 3 * PSZ;                  // 8192*768
  u16* vt_b   = xb;                               // reuse: x dead after gemm_qkv

  cvt_bf16_k<<<(MTOK * DIM / 4 + 255) / 256, 256, 0, stream>>>(x, xb, MTOK * DIM / 4);
  cvt_t_k<<<dim3(NQKV / 32, DIM / 32), 256, 0, stream>>>(Wqkv, wqkvt, DIM, NQKV);
  cvt_t_k<<<dim3(DIM / 32, DIM / 32), 256, 0, stream>>>(Wproj, wprojt, DIM, DIM);

  gemm_qkv<<<dim3(NQKV / 128, MTOK / 256), 256, 0, stream>>>(xb, wqkvt, bqkv, qkv_b);

  vt_k<<<dim3(SEQ / 64, BATCH * HEADS), 256, 0, stream>>>(qkv_b + 2 * PSZ, vt_b);

  attn_k<<<dim3(SEQ / 64, BATCH * HEADS), 256, 0, stream>>>(
      qkv_b, qkv_b + PSZ, vt_b, y_b);

  gemm_proj<<<dim3(DIM / 128, MTOK / 128), 256, 0, stream>>>(y_b, wprojt, bproj, out);
}

// Round 6
// 220.964 us; speedup vs baseline: 1.3542x; 1.0284x over previous
//
#include <hip/hip_runtime.h>

typedef unsigned short u16;
typedef __attribute__((ext_vector_type(8))) short short8;
typedef __attribute__((ext_vector_type(4))) short short4v;
typedef __attribute__((ext_vector_type(2))) int int2v;
typedef __attribute__((ext_vector_type(4))) float f32x4;

#define DIM   768
#define HEADS 12
#define HD    64
#define BATCH 8
#define SEQ   1024
#define MTOK  (BATCH*SEQ)   /* 8192 */
#define NQKV  (3*DIM)       /* 2304 */
#define KPAD  72            /* attn LDS row stride: 36 dwords breaks 32-bank alias */
#define EPAD  66            /* gemm epilogue stage stride */
#define PSZ   ((size_t)BATCH*HEADS*SEQ*HD)   /* one of q/k/v */
#define SCQ   0.1803368801f /* hd^-0.5 * log2(e), folded into stored q */

__device__ __forceinline__ u16 f2bf(float f) {
  unsigned x = __float_as_uint(f);
  x += 0x7fffu + ((x >> 16) & 1u);      // RNE
  return (u16)(x >> 16);
}

__device__ __forceinline__ void gload16(const u16* g, u16* l) {
  __builtin_amdgcn_global_load_lds(
      (const __attribute__((address_space(1))) unsigned int*)g,
      (__attribute__((address_space(3))) unsigned int*)l, 16, 0, 0);
}

// ---------------- fused conversions: x->bf16, Wqkv^T, Wproj^T ----------------
#define XBLK 6144            /* MTOK*DIM/4/256 */
#define QTBLK 1728           /* (NQKV/32)*(DIM/32) */
__global__ void cvt_all_k(const float* __restrict__ x,
                          const float* __restrict__ Wqkv,
                          const float* __restrict__ Wproj,
                          u16* __restrict__ xb, u16* __restrict__ wqkvt,
                          u16* __restrict__ wprojt) {
  __shared__ u16 tile[32][33];
  const int blk = blockIdx.x;
  if (blk < XBLK) {
    const int i = blk * 256 + threadIdx.x;
    float4 f = ((const float4*)x)[i];
    short4v o;
    o.x = (short)f2bf(f.x); o.y = (short)f2bf(f.y);
    o.z = (short)f2bf(f.z); o.w = (short)f2bf(f.w);
    ((short4v*)xb)[i] = o;
    return;
  }
  const float* in; u16* out; int K, N, n0, k0;
  if (blk < XBLK + QTBLK) {
    const int t = blk - XBLK;
    in = Wqkv; out = wqkvt; K = DIM; N = NQKV;
    n0 = (t % (NQKV / 32)) * 32; k0 = (t / (NQKV / 32)) * 32;
  } else {
    const int t = blk - XBLK - QTBLK;
    in = Wproj; out = wprojt; K = DIM; N = DIM;
    n0 = (t % (DIM / 32)) * 32; k0 = (t / (DIM / 32)) * 32;
  }
  const int tx = threadIdx.x & 31, ty = threadIdx.x >> 5;
  #pragma unroll
  for (int i = 0; i < 32; i += 8)
    tile[ty + i][tx] = f2bf(in[(size_t)(k0 + ty + i) * N + n0 + tx]);
  __syncthreads();
  #pragma unroll
  for (int i = 0; i < 32; i += 8)
    out[(size_t)(n0 + ty + i) * K + k0 + tx] = tile[tx][ty + i];
}

// ---------------- GEMM1: qkv = x * Wqkv^T + b, 256x128 tile ----------------
// qkv layout: [part][bh][t][d]; q pre-scaled by SCQ; LDS-transpose epilogue
__global__ __launch_bounds__(256, 2)
void gemm_qkv(const u16* __restrict__ A, const u16* __restrict__ Bt,
              const float* __restrict__ bias, u16* __restrict__ qkv) {
  __shared__ __align__(16) u16 smem[256 * 32 + 128 * 32];
  u16* lA = smem;
  u16* lB = smem + 256 * 32;
  const int w = threadIdx.x >> 6, lane = threadIdx.x & 63;
  const int l15 = lane & 15, quad = lane >> 4;
  const int m0 = blockIdx.y * 256, n0 = blockIdx.x * 128;
  const int wm = (w >> 1) * 128, wn = (w & 1) * 64;

  f32x4 acc[8][4] = {};

  const int ar = threadIdx.x >> 2, ak = (threadIdx.x & 3) * 8;
  const u16* ga = A  + (size_t)(m0 + ar) * DIM + ak;
  const u16* gb = Bt + (size_t)(n0 + ar) * DIM + ak;
  u16* la = &lA[threadIdx.x * 8];
  u16* lb = &lB[threadIdx.x * 8];

  for (int k0 = 0; k0 < DIM; k0 += 32) {
    #pragma unroll
    for (int t = 0; t < 4; ++t) gload16(ga + (size_t)t * 64 * DIM + k0, la + t * 2048);
    #pragma unroll
    for (int t = 0; t < 2; ++t) gload16(gb + (size_t)t * 64 * DIM + k0, lb + t * 2048);
    __syncthreads();

    short8 af[8], bfr[4];
    #pragma unroll
    for (int mt = 0; mt < 8; ++mt)
      af[mt] = *(const short8*)&lA[(wm + mt * 16 + l15) * 32 + quad * 8];
    #pragma unroll
    for (int nt = 0; nt < 4; ++nt)
      bfr[nt] = *(const short8*)&lB[(wn + nt * 16 + l15) * 32 + quad * 8];
    #pragma unroll
    for (int mt = 0; mt < 8; ++mt)
      #pragma unroll
      for (int nt = 0; nt < 4; ++nt)
        acc[mt][nt] = __builtin_amdgcn_mfma_f32_16x16x32_bf16(af[mt], bfr[nt], acc[mt][nt], 0, 0, 0);
    __syncthreads();
  }

  const int bb = m0 >> 10;
  const int tb0 = (m0 & 1023) + wm;
  const int nh = n0 + wn;
  const int part = nh / DIM, idx = nh - part * DIM;
  const int h = idx >> 6;
  u16* dstbase = qkv + part * PSZ + ((size_t)(bb * HEADS + h) * SEQ + tb0) * HD;
  const float qsc = (part == 0) ? SCQ : 1.0f;   // fold softmax scale into q

  float bnl[4];
  #pragma unroll
  for (int nt = 0; nt < 4; ++nt) bnl[nt] = bias[nh + nt * 16 + l15];

  const int erow = lane >> 3, ec8 = (lane & 7) * 8;
  #pragma unroll
  for (int mt = 0; mt < 8; ++mt) {
    u16* ep = smem + w * (16 * EPAD) + (mt & 1) * (4 * 16 * EPAD);
    #pragma unroll
    for (int nt = 0; nt < 4; ++nt)
      #pragma unroll
      for (int r = 0; r < 4; ++r)
        ep[(quad * 4 + r) * EPAD + nt * 16 + l15] = f2bf((acc[mt][nt][r] + bnl[nt]) * qsc);
    #pragma unroll
    for (int j = 0; j < 2; ++j) {
      const int trow = j * 8 + erow;
      short8 vrow = *(const short8*)&ep[trow * EPAD + ec8];
      *(short8*)(dstbase + (size_t)(mt * 16 + trow) * HD + ec8) = vrow;
    }
  }
}

// ---------------- v [bh][t][d] -> vt [bh][d][t]  (bf16 transpose) ----------------
__global__ void vt_k(const u16* __restrict__ v, u16* __restrict__ vt) {
  __shared__ u16 tl[64][72];
  const int bh = blockIdx.y, t0 = blockIdx.x * 64;
  #pragma unroll
  for (int i = 0; i < 2; ++i) {
    const int c = threadIdx.x + i * 256;
    const int tr = c >> 3, dc8 = c & 7;
    const int cc = dc8 ^ (tr >> 3);
    *(short8*)&tl[tr][cc * 8] = *(const short8*)(v + ((size_t)bh * SEQ + t0 + tr) * HD + dc8 * 8);
  }
  __syncthreads();
  #pragma unroll
  for (int i = 0; i < 2; ++i) {
    const int c = threadIdx.x + i * 256;
    const int dr = c >> 3, tc = (c & 7) * 8;
    short8 outv;
    #pragma unroll
    for (int j = 0; j < 8; ++j) {
      const int t = tc + j;
      const int cc = (dr >> 3) ^ (t >> 3);
      outv[j] = (short)tl[t][cc * 8 + (dr & 7)];
    }
    *(short8*)(vt + ((size_t)bh * HD + dr) * SEQ + t0 + tc) = outv;
  }
}

// ---------------- GEMM2: out = y * Wproj^T + b (fp32 out, 128x128) ----------------
__global__ __launch_bounds__(256)
void gemm_proj(const u16* __restrict__ A, const u16* __restrict__ Bt,
               const float* __restrict__ bias, float* __restrict__ outF) {
  __shared__ __align__(16) u16 lA[128 * 32];
  __shared__ __align__(16) u16 lB[128 * 32];
  const int w = threadIdx.x >> 6, lane = threadIdx.x & 63;
  const int l15 = lane & 15, quad = lane >> 4;
  const int m0 = blockIdx.y * 128, n0 = blockIdx.x * 128;
  const int wm = (w >> 1) * 64, wn = (w & 1) * 64;

  f32x4 acc[4][4] = {};

  const int rr = lane >> 2;
  const int cc = (lane & 3) * 8;
  const u16* ga0 = A  + (size_t)(m0 + w * 32 + rr) * DIM + cc;
  const u16* gb0 = Bt + (size_t)(n0 + w * 32 + rr) * DIM + cc;
  u16* la0 = &lA[w * 1024];
  u16* lb0 = &lB[w * 1024];

  for (int k0 = 0; k0 < DIM; k0 += 32) {
    gload16(ga0 + k0,            la0);
    gload16(ga0 + 16 * DIM + k0, la0 + 512);
    gload16(gb0 + k0,            lb0);
    gload16(gb0 + 16 * DIM + k0, lb0 + 512);
    __syncthreads();

    short8 af[4], bfr[4];
    #pragma unroll
    for (int mt = 0; mt < 4; ++mt)
      af[mt] = *(const short8*)&lA[(wm + mt * 16 + l15) * 32 + quad * 8];
    #pragma unroll
    for (int nt = 0; nt < 4; ++nt)
      bfr[nt] = *(const short8*)&lB[(wn + nt * 16 + l15) * 32 + quad * 8];
    #pragma unroll
    for (int mt = 0; mt < 4; ++mt)
      #pragma unroll
      for (int nt = 0; nt < 4; ++nt)
        acc[mt][nt] = __builtin_amdgcn_mfma_f32_16x16x32_bf16(af[mt], bfr[nt], acc[mt][nt], 0, 0, 0);
    __syncthreads();
  }

  #pragma unroll
  for (int nt = 0; nt < 4; ++nt) {
    const int n = n0 + wn + nt * 16 + l15;
    const float bn = bias[n];
    #pragma unroll
    for (int mt = 0; mt < 4; ++mt)
      #pragma unroll
      for (int r = 0; r < 4; ++r) {
        const int m = m0 + wm + mt * 16 + quad * 4 + r;
        outF[(size_t)m * DIM + n] = acc[mt][nt][r] + bn;
      }
  }
}

// ---------------- flash attention: 128-row Q tiles, S^T, max-free ----------------
// grid (8, 96). block 256 = 4 waves x 32 q-rows (2 q-groups of 16).
__global__ __launch_bounds__(256)
void attn_k(const u16* __restrict__ qb, const u16* __restrict__ kb,
            const u16* __restrict__ vtb, u16* __restrict__ yb) {
  const int qt = blockIdx.x, bh = blockIdx.y;
  const int w = threadIdx.x >> 6, lane = threadIdx.x & 63;
  const int l15 = lane & 15, quad = lane >> 4;

  __shared__ __align__(16) u16 lK[64 * KPAD];      // [key][d]
  __shared__ __align__(16) u16 lV[64 * KPAD];      // [d][key]
  __shared__ __align__(16) u16 lP[4][32 * KPAD];   // per-wave [qrow 0..31][key]

  // Q pre-scaled by SCQ in gemm_qkv; serves as B-operand of S^T = K * Q^T
  const u16* qb0 = qb + ((size_t)bh * SEQ + qt * 128 + w * 32 + l15) * HD;
  short8 aq[2][2];
  #pragma unroll
  for (int qg = 0; qg < 2; ++qg) {
    aq[qg][0] = *(const short8*)(qb0 + (size_t)qg * 16 * HD + quad * 8);
    aq[qg][1] = *(const short8*)(qb0 + (size_t)qg * 16 * HD + 32 + quad * 8);
  }

  f32x4 o[2][4] = {};
  float rs[2] = {0.f, 0.f};

  const u16* kcbase = kb + (size_t)bh * SEQ * HD;
  const u16* vbase  = vtb + (size_t)bh * HD * SEQ;
  u16* lPw = &lP[w][0];

  for (int kc = 0; kc < 16; ++kc) {
    const u16* kg = kcbase + kc * 64 * HD;
    #pragma unroll
    for (int i = 0; i < 2; ++i) {
      const int cid = threadIdx.x + i * 256;
      *(short8*)&lK[(cid >> 3) * KPAD + (cid & 7) * 8] = *(const short8*)(kg + cid * 8);
    }
    #pragma unroll
    for (int i = 0; i < 2; ++i) {
      const int cid = threadIdx.x + i * 256;
      const int d = cid >> 3, c8 = (cid & 7) * 8;
      *(short8*)&lV[d * KPAD + c8] = *(const short8*)(vbase + (size_t)d * SEQ + kc * 64 + c8);
    }
    __syncthreads();

    // K and V fragments: load once, shared across both q-groups
    short8 ak0[4], ak1[4], bv0[4], bv1[4];
    #pragma unroll
    for (int nt = 0; nt < 4; ++nt) {
      ak0[nt] = *(const short8*)&lK[(nt * 16 + l15) * KPAD + quad * 8];
      ak1[nt] = *(const short8*)&lK[(nt * 16 + l15) * KPAD + 32 + quad * 8];
      bv0[nt] = *(const short8*)&lV[(nt * 16 + l15) * KPAD + quad * 8];
      bv1[nt] = *(const short8*)&lV[(nt * 16 + l15) * KPAD + 32 + quad * 8];
    }

    #pragma unroll
    for (int qg = 0; qg < 2; ++qg) {
      f32x4 st[4] = {};
      #pragma unroll
      for (int nt = 0; nt < 4; ++nt) {
        st[nt] = __builtin_amdgcn_mfma_f32_16x16x32_bf16(ak0[nt], aq[qg][0], st[nt], 0, 0, 0);
        st[nt] = __builtin_amdgcn_mfma_f32_16x16x32_bf16(ak1[nt], aq[qg][1], st[nt], 0, 0, 0);
      }

      // max-free softmax, truncation-matched: sum the SAME truncated values
      // that enter PV, so quantization cancels in the final ratio.
      #pragma unroll
      for (int nt = 0; nt < 4; ++nt) {
        float p0 = __builtin_amdgcn_exp2f(st[nt][0]);
        float p1 = __builtin_amdgcn_exp2f(st[nt][1]);
        float p2 = __builtin_amdgcn_exp2f(st[nt][2]);
        float p3 = __builtin_amdgcn_exp2f(st[nt][3]);
        float t0 = __uint_as_float(__float_as_uint(p0) & 0xffff0000u);
        float t1 = __uint_as_float(__float_as_uint(p1) & 0xffff0000u);
        float t2 = __uint_as_float(__float_as_uint(p2) & 0xffff0000u);
        float t3 = __uint_as_float(__float_as_uint(p3) & 0xffff0000u);
        rs[qg] += (t0 + t1) + (t2 + t3);
        int2v pk;
        pk.x = (int)__builtin_amdgcn_perm(__float_as_uint(p1), __float_as_uint(p0), 0x07060302u);
        pk.y = (int)__builtin_amdgcn_perm(__float_as_uint(p3), __float_as_uint(p2), 0x07060302u);
        *(int2v*)&lPw[(qg * 16 + l15) * KPAD + nt * 16 + quad * 4] = pk;
      }
      const short8 ap0 = *(const short8*)&lPw[(qg * 16 + l15) * KPAD + quad * 8];
      const short8 ap1 = *(const short8*)&lPw[(qg * 16 + l15) * KPAD + 32 + quad * 8];
      #pragma unroll
      for (int nt = 0; nt < 4; ++nt) {
        o[qg][nt] = __builtin_amdgcn_mfma_f32_16x16x32_bf16(ap0, bv0[nt], o[qg][nt], 0, 0, 0);
        o[qg][nt] = __builtin_amdgcn_mfma_f32_16x16x32_bf16(ap1, bv1[nt], o[qg][nt], 0, 0, 0);
      }
    }
    __syncthreads();
  }

  const int b = bh / HEADS, h = bh % HEADS;
  #pragma unroll
  for (int qg = 0; qg < 2; ++qg) {
    rs[qg] += __shfl_xor(rs[qg], 16);
    rs[qg] += __shfl_xor(rs[qg], 32);
    #pragma unroll
    for (int r = 0; r < 4; ++r) {
      const float inv = 1.0f / __shfl(rs[qg], quad * 4 + r, 16);
      #pragma unroll
      for (int nt = 0; nt < 4; ++nt)
        lPw[(qg * 16 + quad * 4 + r) * KPAD + nt * 16 + l15] = f2bf(o[qg][nt][r] * inv);
    }
  }

  u16* dst = yb + ((size_t)b * SEQ + qt * 128 + w * 32) * DIM + h * HD;
  const int erow = lane >> 3, ec8 = (lane & 7) * 8;
  #pragma unroll
  for (int j = 0; j < 4; ++j) {
    const int trow = j * 8 + erow;
    short8 vrow = *(const short8*)&lPw[trow * KPAD + ec8];
    *(short8*)(dst + (size_t)trow * DIM + ec8) = vrow;   // 128B full-line rows
  }
}

// ---------------- launcher ----------------
extern "C" void kernel_launch(void* const* d_in, const int* in_sizes, int n_in,
                              void* d_out, int out_size, void* d_ws, size_t ws_size,
                              hipStream_t stream) {
  const float* x     = (const float*)d_in[0];
  const float* Wqkv  = (const float*)d_in[1];
  const float* bqkv  = (const float*)d_in[2];
  const float* Wproj = (const float*)d_in[3];
  const float* bproj = (const float*)d_in[4];
  float* out = (float*)d_out;

  u16* xb     = (u16*)d_ws;                       // 8192*768 (reused as vt later)
  u16* wqkvt  = xb + (size_t)MTOK * DIM;
  u16* wprojt = wqkvt + (size_t)NQKV * DIM;
  u16* qkv_b  = wprojt + (size_t)DIM * DIM;       // [part][bh][t][d]
  u16* y_b    = qkv_b + 3 * PSZ;
  u16* vt_b   = xb;

  cvt_all_k<<<XBLK + QTBLK + (DIM / 32) * (DIM / 32), 256, 0, stream>>>(
      x, Wqkv, Wproj, xb, wqkvt, wprojt);

  gemm_qkv<<<dim3(NQKV / 128, MTOK / 256), 256, 0, stream>>>(xb, wqkvt, bqkv, qkv_b);

  vt_k<<<dim3(SEQ / 64, BATCH * HEADS), 256, 0, stream>>>(qkv_b + 2 * PSZ, vt_b);

  attn_k<<<dim3(SEQ / 128, BATCH * HEADS), 256, 0, stream>>>(
      qkv_b, qkv_b + PSZ, vt_b, y_b);

  gemm_proj<<<dim3(DIM / 128, MTOK / 128), 256, 0, stream>>>(y_b, wprojt, bproj, out);
}

// Round 7
// 202.806 us; speedup vs baseline: 1.4754x; 1.0895x over previous
//
#include <hip/hip_runtime.h>

typedef unsigned short u16;
typedef __attribute__((ext_vector_type(8))) short short8;
typedef __attribute__((ext_vector_type(4))) short short4v;
typedef __attribute__((ext_vector_type(2))) int int2v;
typedef __attribute__((ext_vector_type(4))) float f32x4;

#define DIM   768
#define HEADS 12
#define HD    64
#define BATCH 8
#define SEQ   1024
#define MTOK  (BATCH*SEQ)   /* 8192 */
#define NQKV  (3*DIM)       /* 2304 */
#define KPAD  72            /* attn LDS row stride: 36 dwords breaks 32-bank alias */
#define EPAD  66            /* gemm epilogue stage stride */
#define PSZ   ((size_t)BATCH*HEADS*SEQ*HD)   /* one of q/k/v */
#define SCQ   0.1803368801f /* hd^-0.5 * log2(e), folded into stored q */

__device__ __forceinline__ u16 f2bf(float f) {
  unsigned x = __float_as_uint(f);
  x += 0x7fffu + ((x >> 16) & 1u);      // RNE
  return (u16)(x >> 16);
}

__device__ __forceinline__ void gload16(const u16* g, u16* l) {
  __builtin_amdgcn_global_load_lds(
      (const __attribute__((address_space(1))) unsigned int*)g,
      (__attribute__((address_space(3))) unsigned int*)l, 16, 0, 0);
}

// ---------------- fused conversions: x->bf16, Wqkv^T, Wproj^T ----------------
#define XBLK 6144            /* MTOK*DIM/4/256 */
#define QTBLK 1728           /* (NQKV/32)*(DIM/32) */
__global__ void cvt_all_k(const float* __restrict__ x,
                          const float* __restrict__ Wqkv,
                          const float* __restrict__ Wproj,
                          u16* __restrict__ xb, u16* __restrict__ wqkvt,
                          u16* __restrict__ wprojt) {
  __shared__ u16 tile[32][33];
  const int blk = blockIdx.x;
  if (blk < XBLK) {
    const int i = blk * 256 + threadIdx.x;
    float4 f = ((const float4*)x)[i];
    short4v o;
    o.x = (short)f2bf(f.x); o.y = (short)f2bf(f.y);
    o.z = (short)f2bf(f.z); o.w = (short)f2bf(f.w);
    ((short4v*)xb)[i] = o;
    return;
  }
  const float* in; u16* out; int K, N, n0, k0;
  if (blk < XBLK + QTBLK) {
    const int t = blk - XBLK;
    in = Wqkv; out = wqkvt; K = DIM; N = NQKV;
    n0 = (t % (NQKV / 32)) * 32; k0 = (t / (NQKV / 32)) * 32;
  } else {
    const int t = blk - XBLK - QTBLK;
    in = Wproj; out = wprojt; K = DIM; N = DIM;
    n0 = (t % (DIM / 32)) * 32; k0 = (t / (DIM / 32)) * 32;
  }
  const int tx = threadIdx.x & 31, ty = threadIdx.x >> 5;
  #pragma unroll
  for (int i = 0; i < 32; i += 8)
    tile[ty + i][tx] = f2bf(in[(size_t)(k0 + ty + i) * N + n0 + tx]);
  __syncthreads();
  #pragma unroll
  for (int i = 0; i < 32; i += 8)
    out[(size_t)(n0 + ty + i) * K + k0 + tx] = tile[tx][ty + i];
}

// ---------------- GEMM1: qkv = x * Wqkv^T + b, 256x128 tile, BK=64 ----------------
// BK=64 as two side-by-side BK=32 sub-tiles: 12 barrier-drains instead of 24.
__global__ __launch_bounds__(256, 2)
void gemm_qkv(const u16* __restrict__ A, const u16* __restrict__ Bt,
              const float* __restrict__ bias, u16* __restrict__ qkv) {
  __shared__ __align__(16) u16 smem[2 * 256 * 32 + 2 * 128 * 32];  // 48 KB
  u16* lA0 = smem;
  u16* lA1 = smem + 256 * 32;
  u16* lB0 = smem + 2 * 256 * 32;
  u16* lB1 = lB0 + 128 * 32;
  const int w = threadIdx.x >> 6, lane = threadIdx.x & 63;
  const int l15 = lane & 15, quad = lane >> 4;
  const int m0 = blockIdx.y * 256, n0 = blockIdx.x * 128;
  const int wm = (w >> 1) * 128, wn = (w & 1) * 64;

  f32x4 acc[8][4] = {};

  const int ar = threadIdx.x >> 2, ak = (threadIdx.x & 3) * 8;
  const u16* ga = A  + (size_t)(m0 + ar) * DIM + ak;
  const u16* gb = Bt + (size_t)(n0 + ar) * DIM + ak;
  const int lo = threadIdx.x * 8;

  for (int k0 = 0; k0 < DIM; k0 += 64) {
    #pragma unroll
    for (int t = 0; t < 4; ++t) {
      gload16(ga + (size_t)t * 64 * DIM + k0,      lA0 + lo + t * 2048);
      gload16(ga + (size_t)t * 64 * DIM + k0 + 32, lA1 + lo + t * 2048);
    }
    #pragma unroll
    for (int t = 0; t < 2; ++t) {
      gload16(gb + (size_t)t * 64 * DIM + k0,      lB0 + lo + t * 2048);
      gload16(gb + (size_t)t * 64 * DIM + k0 + 32, lB1 + lo + t * 2048);
    }
    __syncthreads();

    #pragma unroll
    for (int kh = 0; kh < 2; ++kh) {
      const u16* lAh = kh ? lA1 : lA0;
      const u16* lBh = kh ? lB1 : lB0;
      short8 af[8], bfr[4];
      #pragma unroll
      for (int mt = 0; mt < 8; ++mt)
        af[mt] = *(const short8*)&lAh[(wm + mt * 16 + l15) * 32 + quad * 8];
      #pragma unroll
      for (int nt = 0; nt < 4; ++nt)
        bfr[nt] = *(const short8*)&lBh[(wn + nt * 16 + l15) * 32 + quad * 8];
      #pragma unroll
      for (int mt = 0; mt < 8; ++mt)
        #pragma unroll
        for (int nt = 0; nt < 4; ++nt)
          acc[mt][nt] = __builtin_amdgcn_mfma_f32_16x16x32_bf16(af[mt], bfr[nt], acc[mt][nt], 0, 0, 0);
    }
    __syncthreads();
  }

  const int bb = m0 >> 10;
  const int tb0 = (m0 & 1023) + wm;
  const int nh = n0 + wn;
  const int part = nh / DIM, idx = nh - part * DIM;
  const int h = idx >> 6;
  u16* dstbase = qkv + part * PSZ + ((size_t)(bb * HEADS + h) * SEQ + tb0) * HD;
  const float qsc = (part == 0) ? SCQ : 1.0f;   // fold softmax scale into q

  float bnl[4];
  #pragma unroll
  for (int nt = 0; nt < 4; ++nt) bnl[nt] = bias[nh + nt * 16 + l15];

  const int erow = lane >> 3, ec8 = (lane & 7) * 8;
  #pragma unroll
  for (int mt = 0; mt < 8; ++mt) {
    u16* ep = smem + w * (16 * EPAD) + (mt & 1) * (4 * 16 * EPAD);
    #pragma unroll
    for (int nt = 0; nt < 4; ++nt)
      #pragma unroll
      for (int r = 0; r < 4; ++r)
        ep[(quad * 4 + r) * EPAD + nt * 16 + l15] = f2bf((acc[mt][nt][r] + bnl[nt]) * qsc);
    #pragma unroll
    for (int j = 0; j < 2; ++j) {
      const int trow = j * 8 + erow;
      short8 vrow = *(const short8*)&ep[trow * EPAD + ec8];
      *(short8*)(dstbase + (size_t)(mt * 16 + trow) * HD + ec8) = vrow;
    }
  }
}

// ---------------- v [bh][t][d] -> vt [bh][d][t]  (bf16 transpose) ----------------
__global__ void vt_k(const u16* __restrict__ v, u16* __restrict__ vt) {
  __shared__ u16 tl[64][72];
  const int bh = blockIdx.y, t0 = blockIdx.x * 64;
  #pragma unroll
  for (int i = 0; i < 2; ++i) {
    const int c = threadIdx.x + i * 256;
    const int tr = c >> 3, dc8 = c & 7;
    const int cc = dc8 ^ (tr >> 3);
    *(short8*)&tl[tr][cc * 8] = *(const short8*)(v + ((size_t)bh * SEQ + t0 + tr) * HD + dc8 * 8);
  }
  __syncthreads();
  #pragma unroll
  for (int i = 0; i < 2; ++i) {
    const int c = threadIdx.x + i * 256;
    const int dr = c >> 3, tc = (c & 7) * 8;
    short8 outv;
    #pragma unroll
    for (int j = 0; j < 8; ++j) {
      const int t = tc + j;
      const int cc = (dr >> 3) ^ (t >> 3);
      outv[j] = (short)tl[t][cc * 8 + (dr & 7)];
    }
    *(short8*)(vt + ((size_t)bh * HD + dr) * SEQ + t0 + tc) = outv;
  }
}

// ---------------- GEMM2: out = y * Wproj^T + b (fp32 out, 128x128, BK=64) ----------------
__global__ __launch_bounds__(256)
void gemm_proj(const u16* __restrict__ A, const u16* __restrict__ Bt,
               const float* __restrict__ bias, float* __restrict__ outF) {
  __shared__ __align__(16) u16 smem[4 * 128 * 32];   // 32 KB
  u16* lA0 = smem;
  u16* lA1 = smem + 128 * 32;
  u16* lB0 = smem + 2 * 128 * 32;
  u16* lB1 = smem + 3 * 128 * 32;
  const int w = threadIdx.x >> 6, lane = threadIdx.x & 63;
  const int l15 = lane & 15, quad = lane >> 4;
  const int m0 = blockIdx.y * 128, n0 = blockIdx.x * 128;
  const int wm = (w >> 1) * 64, wn = (w & 1) * 64;

  f32x4 acc[4][4] = {};

  const int ar = threadIdx.x >> 2, ak = (threadIdx.x & 3) * 8;
  const u16* ga = A  + (size_t)(m0 + ar) * DIM + ak;
  const u16* gb = Bt + (size_t)(n0 + ar) * DIM + ak;
  const int lo = threadIdx.x * 8;

  for (int k0 = 0; k0 < DIM; k0 += 64) {
    #pragma unroll
    for (int t = 0; t < 2; ++t) {
      gload16(ga + (size_t)t * 64 * DIM + k0,      lA0 + lo + t * 2048);
      gload16(ga + (size_t)t * 64 * DIM + k0 + 32, lA1 + lo + t * 2048);
      gload16(gb + (size_t)t * 64 * DIM + k0,      lB0 + lo + t * 2048);
      gload16(gb + (size_t)t * 64 * DIM + k0 + 32, lB1 + lo + t * 2048);
    }
    __syncthreads();

    #pragma unroll
    for (int kh = 0; kh < 2; ++kh) {
      const u16* lAh = kh ? lA1 : lA0;
      const u16* lBh = kh ? lB1 : lB0;
      short8 af[4], bfr[4];
      #pragma unroll
      for (int mt = 0; mt < 4; ++mt)
        af[mt] = *(const short8*)&lAh[(wm + mt * 16 + l15) * 32 + quad * 8];
      #pragma unroll
      for (int nt = 0; nt < 4; ++nt)
        bfr[nt] = *(const short8*)&lBh[(wn + nt * 16 + l15) * 32 + quad * 8];
      #pragma unroll
      for (int mt = 0; mt < 4; ++mt)
        #pragma unroll
        for (int nt = 0; nt < 4; ++nt)
          acc[mt][nt] = __builtin_amdgcn_mfma_f32_16x16x32_bf16(af[mt], bfr[nt], acc[mt][nt], 0, 0, 0);
    }
    __syncthreads();
  }

  #pragma unroll
  for (int nt = 0; nt < 4; ++nt) {
    const int n = n0 + wn + nt * 16 + l15;
    const float bn = bias[n];
    #pragma unroll
    for (int mt = 0; mt < 4; ++mt)
      #pragma unroll
      for (int r = 0; r < 4; ++r) {
        const int m = m0 + wm + mt * 16 + quad * 4 + r;
        outF[(size_t)m * DIM + n] = acc[mt][nt][r] + bn;
      }
  }
}

// ---------------- flash attention: 128-row Q tiles, S^T, max-free ----------------
// grid (8, 96). block 256 = 4 waves x 32 q-rows (2 q-groups of 16).
__global__ __launch_bounds__(256)
void attn_k(const u16* __restrict__ qb, const u16* __restrict__ kb,
            const u16* __restrict__ vtb, u16* __restrict__ yb) {
  const int qt = blockIdx.x, bh = blockIdx.y;
  const int w = threadIdx.x >> 6, lane = threadIdx.x & 63;
  const int l15 = lane & 15, quad = lane >> 4;

  __shared__ __align__(16) u16 lK[64 * KPAD];      // [key][d]
  __shared__ __align__(16) u16 lV[64 * KPAD];      // [d][key]
  __shared__ __align__(16) u16 lP[4][32 * KPAD];   // per-wave [qrow 0..31][key]

  const u16* qb0 = qb + ((size_t)bh * SEQ + qt * 128 + w * 32 + l15) * HD;
  short8 aq[2][2];
  #pragma unroll
  for (int qg = 0; qg < 2; ++qg) {
    aq[qg][0] = *(const short8*)(qb0 + (size_t)qg * 16 * HD + quad * 8);
    aq[qg][1] = *(const short8*)(qb0 + (size_t)qg * 16 * HD + 32 + quad * 8);
  }

  f32x4 o[2][4] = {};
  float rs[2] = {0.f, 0.f};

  const u16* kcbase = kb + (size_t)bh * SEQ * HD;
  const u16* vbase  = vtb + (size_t)bh * HD * SEQ;
  u16* lPw = &lP[w][0];

  for (int kc = 0; kc < 16; ++kc) {
    const u16* kg = kcbase + kc * 64 * HD;
    #pragma unroll
    for (int i = 0; i < 2; ++i) {
      const int cid = threadIdx.x + i * 256;
      *(short8*)&lK[(cid >> 3) * KPAD + (cid & 7) * 8] = *(const short8*)(kg + cid * 8);
    }
    #pragma unroll
    for (int i = 0; i < 2; ++i) {
      const int cid = threadIdx.x + i * 256;
      const int d = cid >> 3, c8 = (cid & 7) * 8;
      *(short8*)&lV[d * KPAD + c8] = *(const short8*)(vbase + (size_t)d * SEQ + kc * 64 + c8);
    }
    __syncthreads();

    short8 ak0[4], ak1[4], bv0[4], bv1[4];
    #pragma unroll
    for (int nt = 0; nt < 4; ++nt) {
      ak0[nt] = *(const short8*)&lK[(nt * 16 + l15) * KPAD + quad * 8];
      ak1[nt] = *(const short8*)&lK[(nt * 16 + l15) * KPAD + 32 + quad * 8];
      bv0[nt] = *(const short8*)&lV[(nt * 16 + l15) * KPAD + quad * 8];
      bv1[nt] = *(const short8*)&lV[(nt * 16 + l15) * KPAD + 32 + quad * 8];
    }

    #pragma unroll
    for (int qg = 0; qg < 2; ++qg) {
      f32x4 st[4] = {};
      #pragma unroll
      for (int nt = 0; nt < 4; ++nt) {
        st[nt] = __builtin_amdgcn_mfma_f32_16x16x32_bf16(ak0[nt], aq[qg][0], st[nt], 0, 0, 0);
        st[nt] = __builtin_amdgcn_mfma_f32_16x16x32_bf16(ak1[nt], aq[qg][1], st[nt], 0, 0, 0);
      }

      #pragma unroll
      for (int nt = 0; nt < 4; ++nt) {
        float p0 = __builtin_amdgcn_exp2f(st[nt][0]);
        float p1 = __builtin_amdgcn_exp2f(st[nt][1]);
        float p2 = __builtin_amdgcn_exp2f(st[nt][2]);
        float p3 = __builtin_amdgcn_exp2f(st[nt][3]);
        float t0 = __uint_as_float(__float_as_uint(p0) & 0xffff0000u);
        float t1 = __uint_as_float(__float_as_uint(p1) & 0xffff0000u);
        float t2 = __uint_as_float(__float_as_uint(p2) & 0xffff0000u);
        float t3 = __uint_as_float(__float_as_uint(p3) & 0xffff0000u);
        rs[qg] += (t0 + t1) + (t2 + t3);
        int2v pk;
        pk.x = (int)__builtin_amdgcn_perm(__float_as_uint(p1), __float_as_uint(p0), 0x07060302u);
        pk.y = (int)__builtin_amdgcn_perm(__float_as_uint(p3), __float_as_uint(p2), 0x07060302u);
        *(int2v*)&lPw[(qg * 16 + l15) * KPAD + nt * 16 + quad * 4] = pk;
      }
      const short8 ap0 = *(const short8*)&lPw[(qg * 16 + l15) * KPAD + quad * 8];
      const short8 ap1 = *(const short8*)&lPw[(qg * 16 + l15) * KPAD + 32 + quad * 8];
      #pragma unroll
      for (int nt = 0; nt < 4; ++nt) {
        o[qg][nt] = __builtin_amdgcn_mfma_f32_16x16x32_bf16(ap0, bv0[nt], o[qg][nt], 0, 0, 0);
        o[qg][nt] = __builtin_amdgcn_mfma_f32_16x16x32_bf16(ap1, bv1[nt], o[qg][nt], 0, 0, 0);
      }
    }
    __syncthreads();
  }

  const int b = bh / HEADS, h = bh % HEADS;
  #pragma unroll
  for (int qg = 0; qg < 2; ++qg) {
    rs[qg] += __shfl_xor(rs[qg], 16);
    rs[qg] += __shfl_xor(rs[qg], 32);
    #pragma unroll
    for (int r = 0; r < 4; ++r) {
      const float inv = 1.0f / __shfl(rs[qg], quad * 4 + r, 16);
      #pragma unroll
      for (int nt = 0; nt < 4; ++nt)
        lPw[(qg * 16 + quad * 4 + r) * KPAD + nt * 16 + l15] = f2bf(o[qg][nt][r] * inv);
    }
  }

  u16* dst = yb + ((size_t)b * SEQ + qt * 128 + w * 32) * DIM + h * HD;
  const int erow = lane >> 3, ec8 = (lane & 7) * 8;
  #pragma unroll
  for (int j = 0; j < 4; ++j) {
    const int trow = j * 8 + erow;
    short8 vrow = *(const short8*)&lPw[trow * KPAD + ec8];
    *(short8*)(dst + (size_t)trow * DIM + ec8) = vrow;
  }
}

// ---------------- launcher ----------------
extern "C" void kernel_launch(void* const* d_in, const int* in_sizes, int n_in,
                              void* d_out, int out_size, void* d_ws, size_t ws_size,
                              hipStream_t stream) {
  const float* x     = (const float*)d_in[0];
  const float* Wqkv  = (const float*)d_in[1];
  const float* bqkv  = (const float*)d_in[2];
  const float* Wproj = (const float*)d_in[3];
  const float* bproj = (const float*)d_in[4];
  float* out = (float*)d_out;

  u16* xb     = (u16*)d_ws;                       // 8192*768 (reused as vt later)
  u16* wqkvt  = xb + (size_t)MTOK * DIM;
  u16* wprojt = wqkvt + (size_t)NQKV * DIM;
  u16* qkv_b  = wprojt + (size_t)DIM * DIM;       // [part][bh][t][d]
  u16* y_b    = qkv_b + 3 * PSZ;
  u16* vt_b   = xb;

  cvt_all_k<<<XBLK + QTBLK + (DIM / 32) * (DIM / 32), 256, 0, stream>>>(
      x, Wqkv, Wproj, xb, wqkvt, wprojt);

  gemm_qkv<<<dim3(NQKV / 128, MTOK / 256), 256, 0, stream>>>(xb, wqkvt, bqkv, qkv_b);

  vt_k<<<dim3(SEQ / 64, BATCH * HEADS), 256, 0, stream>>>(qkv_b + 2 * PSZ, vt_b);

  attn_k<<<dim3(SEQ / 128, BATCH * HEADS), 256, 0, stream>>>(
      qkv_b, qkv_b + PSZ, vt_b, y_b);

  gemm_proj<<<dim3(DIM / 128, MTOK / 128), 256, 0, stream>>>(y_b, wprojt, bproj, out);
}